// Round 10
// baseline (283.793 us; speedup 1.0000x reference)
//
#include <hip/hip_runtime.h>
#include <math.h>

#define BQ 4
#define DM 192
#define DI 384
#define HH 48
#define WW 48
#define LL 2304
#define KK 4
#define NN 16
#define RR 12
#define CH 48      // chunks per sequence
#define CLEN 48    // chunk length

#define LOG2E 1.4426950408889634f
#define LN2   0.6931471805599453f

typedef short v8s __attribute__((ext_vector_type(8)));
typedef float v4f __attribute__((ext_vector_type(4)));

__device__ __forceinline__ float gelu_exact(float x) {
    return 0.5f * x * (1.0f + erff(x * 0.7071067811865476f));
}

__device__ __forceinline__ float fexp2(float x) {
    return __builtin_amdgcn_exp2f(x);
}

__device__ __forceinline__ float flog2(float x) {
    return __builtin_amdgcn_logf(x);
}

// softplus via hw exp2/log2: max(x,0) + ln2*log2(1 + 2^(-|x|*log2e))
__device__ __forceinline__ float softplus_f(float x) {
    float t = fexp2(-fabsf(x) * LOG2E);
    return fmaxf(x, 0.0f) + LN2 * flog2(1.0f + t);
}

__device__ __forceinline__ int pt_of(int p) {   // 48x48 transpose, involution
    return (p % 48) * 48 + p / 48;
}

__device__ __forceinline__ short f2bf(float x) {
    unsigned u = __float_as_uint(x);
    unsigned r = (u + 0x7FFFu + ((u >> 16) & 1u)) >> 16;
    return (short)r;
}

// ---------------- P1: cast weights to bf16. wpbf = x_proj (176,384) padded to 192 rows.
__global__ __launch_bounds__(256) void k_prep_w(const float* __restrict__ ipw,
                                                const float* __restrict__ opw,
                                                const float* __restrict__ xpw,
                                                short* __restrict__ wibf,
                                                short* __restrict__ owbf,
                                                short* __restrict__ wpbf) {
    int i = blockIdx.x * 256 + threadIdx.x;     // 1152*256 = 294912 exactly
    if (i < 147456)       wibf[i] = f2bf(ipw[i]);
    else if (i < 221184)  owbf[i - 147456] = f2bf(opw[i - 147456]);
    else if (i < 288768)  wpbf[i - 221184] = f2bf(xpw[i - 221184]);
    else                  wpbf[67584 + (i - 288768)] = 0;   // pad rows 176..191
}

// ---------------- P2: transpose-cast x (B,192,L) -> xTbf (B,L,192) bf16
__global__ __launch_bounds__(256) void k_prep_xT(const float* __restrict__ x,
                                                 short* __restrict__ xTbf) {
    __shared__ float T[32][33];
    int blk = blockIdx.x;           // (b*72 + lt)*6 + dt
    int dt = blk % 6;
    int lt = (blk / 6) % 72;
    int b  = blk / (6 * 72);
    int d0 = dt * 32, l0 = lt * 32;
    int tx = threadIdx.x & 31, ty = threadIdx.x >> 5;   // ty 0..7
    #pragma unroll
    for (int i = 0; i < 4; ++i) {
        int dd = ty + 8 * i;
        T[dd][tx] = x[(size_t)(b * DM + d0 + dd) * LL + l0 + tx];
    }
    __syncthreads();
    #pragma unroll
    for (int i = 0; i < 4; ++i) {
        int ll = ty + 8 * i;
        xTbf[(size_t)(b * LL + l0 + ll) * DM + d0 + tx] = f2bf(T[tx][ll]);
    }
}

// ---------------- K1: in_proj via bf16 MFMA. D[l][o]; o<384 -> xc, else gelu->z.
__global__ __launch_bounds__(256) void k_inproj_mfma(
    const short* __restrict__ xTbf,   // (B,L,192) bf16
    const short* __restrict__ wibf,   // (768,192) bf16
    float* __restrict__ xcz)          // (B,L,768) fp32
{
    __shared__ short sA[128 * 40];    // [l][k32], row stride 40 shorts
    __shared__ short sB[64 * 40];     // [o][k32]
    int o0 = blockIdx.x * 64;
    int l0 = blockIdx.y * 128;
    int b  = blockIdx.z;
    int tid = threadIdx.x;
    int lane = tid & 63, wid = tid >> 6;
    int n = lane & 15, quad = lane >> 4;

    v4f acc[2][4];
    #pragma unroll
    for (int i = 0; i < 2; ++i)
        #pragma unroll
        for (int j = 0; j < 4; ++j) acc[i][j] = (v4f){0.f, 0.f, 0.f, 0.f};

    for (int kc = 0; kc < 192; kc += 32) {
        for (int i = tid; i < 512; i += 256) {
            int row = i >> 2, seg = i & 3;
            *(v8s*)&sA[row * 40 + seg * 8] =
                *(const v8s*)(xTbf + (size_t)(b * LL + l0 + row) * DM + kc + seg * 8);
        }
        {
            int row = tid >> 2, seg = tid & 3;
            *(v8s*)&sB[row * 40 + seg * 8] =
                *(const v8s*)(wibf + (size_t)(o0 + row) * DM + kc + seg * 8);
        }
        __syncthreads();
        v8s a0 = *(v8s*)&sA[(wid * 32 + n) * 40 + quad * 8];
        v8s a1 = *(v8s*)&sA[(wid * 32 + 16 + n) * 40 + quad * 8];
        #pragma unroll
        for (int os = 0; os < 4; ++os) {
            v8s bv = *(v8s*)&sB[(os * 16 + n) * 40 + quad * 8];
            acc[0][os] = __builtin_amdgcn_mfma_f32_16x16x32_bf16(a0, bv, acc[0][os], 0, 0, 0);
            acc[1][os] = __builtin_amdgcn_mfma_f32_16x16x32_bf16(a1, bv, acc[1][os], 0, 0, 0);
        }
        __syncthreads();
    }
    bool zhalf = (o0 >= DI);
    #pragma unroll
    for (int ls = 0; ls < 2; ++ls)
        #pragma unroll
        for (int os = 0; os < 4; ++os) {
            int o = o0 + os * 16 + n;
            #pragma unroll
            for (int r = 0; r < 4; ++r) {
                int l = l0 + wid * 32 + ls * 16 + quad * 4 + r;
                float v = acc[ls][os][r];
                xcz[(size_t)(b * LL + l) * 768 + o] = zhalf ? gelu_exact(v) : v;
            }
        }
}

// ---------------- K2: depthwise 3x3 conv + bias + gelu, [l][c] layout.
// Writes xcT fp32 (row-major), xcTt fp32 (spatially TRANSPOSED row order:
// row' = pt(row)) and xcTbf bf16. xcTt makes the k=1/k=3 scan directions
// sequential-row walks (u-load stride +-1536B instead of +-73728B).
__global__ __launch_bounds__(384) void k_dwconv(const float* __restrict__ xcz,
                                                const float* __restrict__ cw,
                                                const float* __restrict__ cb,
                                                float* __restrict__ xcT,
                                                float* __restrict__ xcTt,
                                                short* __restrict__ xcTbf) {
    int blk = blockIdx.x;           // ((b*HH + h)*4 + seg)
    int seg = blk & 3;
    int bh = blk >> 2;
    int b = bh / HH, h = bh % HH;
    int d = threadIdx.x;
    int w0 = seg * 12;
    const float* in = xcz + (size_t)b * LL * 768 + d;
    float w9[9];
    #pragma unroll
    for (int i = 0; i < 9; ++i) w9[i] = cw[d * 9 + i];
    float bias = cb[d];
    bool hm = h > 0, hp = h < HH - 1;
    int r0 = (h - 1) * WW, r1 = h * WW, r2 = (h + 1) * WW;
    float c00, c01, c02, c10, c11, c12, c20, c21, c22;
    bool wl = (w0 > 0);
    c00 = (hm && wl) ? in[(size_t)(r0 + w0 - 1) * 768] : 0.f;
    c10 = wl ? in[(size_t)(r1 + w0 - 1) * 768] : 0.f;
    c20 = (hp && wl) ? in[(size_t)(r2 + w0 - 1) * 768] : 0.f;
    c01 = hm ? in[(size_t)(r0 + w0) * 768] : 0.f;
    c11 = in[(size_t)(r1 + w0) * 768];
    c21 = hp ? in[(size_t)(r2 + w0) * 768] : 0.f;
    c02 = hm ? in[(size_t)(r0 + w0 + 1) * 768] : 0.f;
    c12 = in[(size_t)(r1 + w0 + 1) * 768];
    c22 = hp ? in[(size_t)(r2 + w0 + 1) * 768] : 0.f;
    #pragma unroll
    for (int wi = 0; wi < 12; ++wi) {
        int w = w0 + wi;
        float s = bias
            + w9[0] * c00 + w9[1] * c01 + w9[2] * c02
            + w9[3] * c10 + w9[4] * c11 + w9[5] * c12
            + w9[6] * c20 + w9[7] * c21 + w9[8] * c22;
        float v = gelu_exact(s);
        int pos = h * WW + w;
        size_t row  = (size_t)b * LL + pos;
        size_t rowt = (size_t)b * LL + (w * 48 + h);   // pt(pos)
        xcT[row * DI + d] = v;
        xcTt[rowt * DI + d] = v;
        xcTbf[row * DI + d] = f2bf(v);
        c00 = c01; c01 = c02; c10 = c11; c11 = c12; c20 = c21; c21 = c22;
        int wn = w + 2;
        bool okw = wn < WW;
        c02 = (hm && okw) ? in[(size_t)(r0 + wn) * 768] : 0.f;
        c12 = okw ? in[(size_t)(r1 + wn) * 768] : 0.f;
        c22 = (hp && okw) ? in[(size_t)(r2 + wn) * 768] : 0.f;
    }
}

// ---------------- K3: x_proj, ALL 4 directions as ONE bf16 MFMA GEMM.
__global__ __launch_bounds__(256) void k_xproj_mfma(
    const short* __restrict__ xcTbf,  // (B,L,384) bf16
    const short* __restrict__ wpbf,   // (192,384) bf16, rows>=176 zero
    float* __restrict__ dts,
    float* __restrict__ Bsb,
    float* __restrict__ Csb)
{
    __shared__ short sA[128 * 40];
    __shared__ short sB[64 * 40];
    int o0 = blockIdx.x * 64;
    int l0 = blockIdx.y * 128;
    int b  = blockIdx.z;
    int tid = threadIdx.x;
    int lane = tid & 63, wid = tid >> 6;
    int n = lane & 15, quad = lane >> 4;

    v4f acc[2][4];
    #pragma unroll
    for (int i = 0; i < 2; ++i)
        #pragma unroll
        for (int j = 0; j < 4; ++j) acc[i][j] = (v4f){0.f, 0.f, 0.f, 0.f};

    for (int kc = 0; kc < DI; kc += 32) {
        for (int i = tid; i < 512; i += 256) {
            int row = i >> 2, seg = i & 3;
            *(v8s*)&sA[row * 40 + seg * 8] =
                *(const v8s*)(xcTbf + (size_t)(b * LL + l0 + row) * DI + kc + seg * 8);
        }
        {
            int row = tid >> 2, seg = tid & 3;
            *(v8s*)&sB[row * 40 + seg * 8] =
                *(const v8s*)(wpbf + (size_t)(o0 + row) * DI + kc + seg * 8);
        }
        __syncthreads();
        v8s a0 = *(v8s*)&sA[(wid * 32 + n) * 40 + quad * 8];
        v8s a1 = *(v8s*)&sA[(wid * 32 + 16 + n) * 40 + quad * 8];
        #pragma unroll
        for (int os = 0; os < 4; ++os) {
            v8s bv = *(v8s*)&sB[(os * 16 + n) * 40 + quad * 8];
            acc[0][os] = __builtin_amdgcn_mfma_f32_16x16x32_bf16(a0, bv, acc[0][os], 0, 0, 0);
            acc[1][os] = __builtin_amdgcn_mfma_f32_16x16x32_bf16(a1, bv, acc[1][os], 0, 0, 0);
        }
        __syncthreads();
    }
    #pragma unroll
    for (int ls = 0; ls < 2; ++ls)
        #pragma unroll
        for (int os = 0; os < 4; ++os) {
            int c_all = o0 + os * 16 + n;
            if (c_all >= 176) continue;
            int k = c_all / 44;
            int c = c_all - k * 44;
            int bk = b * 4 + k;
            #pragma unroll
            for (int r = 0; r < 4; ++r) {
                int lp = l0 + wid * 32 + ls * 16 + quad * 4 + r;
                int lk = (k == 0) ? lp
                       : (k == 1) ? pt_of(lp)
                       : (k == 2) ? (LL - 1 - lp)
                                  : (LL - 1 - pt_of(lp));
                float v = acc[ls][os][r];
                size_t base = (size_t)bk * LL + lk;
                if (c < RR)           dts[base * RR + c] = v;
                else if (c < RR + NN) Bsb[base * NN + (c - RR)] = v;
                else                  Csb[base * NN + (c - RR - NN)] = v;
            }
        }
}

// ---------------- fat-lane pass1 (R9 structure + sequential-u via xcTt).
// All 4 directions now walk rows at stride +-1 (k=0,2 on xcT; k=1,3 on xcTt:
// pt((l%48)*48+c) = c*48 + l%48 -> base l0 step +1; k=3 mirrors to
// base LL-1-l0 step -1). Kills the 73.7KB-stride latency wall for k=1,3.
__global__ __launch_bounds__(384) void k_scan_pass1(
    const float* __restrict__ xcT,
    const float* __restrict__ xcTt,
    const float* __restrict__ dts,
    const float* __restrict__ Bsb,
    const float* __restrict__ dtw_g,
    const float* __restrict__ dtb_g,
    const float* __restrict__ Alogs,
    float* __restrict__ hstin,
    float* __restrict__ Tsum)
{
    __shared__ float sB[CLEN * 16];      // 3 KB, [l][n]
    int blk = blockIdx.x;            // bk*CH + c
    int c = blk % CH;
    int bk = blk / CH;
    int k = bk & 3, b = bk >> 2;
    int d = threadIdx.x;             // 0..383
    int l0 = c * CLEN;
    int kd = k * DI + d;

    {   // coop stage: 192 float4
        const float4* Bg = (const float4*)(Bsb + ((size_t)bk * LL + l0) * NN);
        if (d < 192) ((float4*)sB)[d] = Bg[d];
    }

    float dtbv = dtb_g[kd];
    float w12[12];
    {
        const float4* p = (const float4*)(dtw_g + (size_t)kd * RR);
        float4 a0 = p[0], a1 = p[1], a2 = p[2];
        w12[0]=a0.x; w12[1]=a0.y; w12[2]=a0.z;  w12[3]=a0.w;
        w12[4]=a1.x; w12[5]=a1.y; w12[6]=a1.z;  w12[7]=a1.w;
        w12[8]=a2.x; w12[9]=a2.y; w12[10]=a2.z; w12[11]=a2.w;
    }
    float A2[16];
    {
        const float4* p = (const float4*)(Alogs + (size_t)kd * NN);
        #pragma unroll
        for (int i = 0; i < 4; ++i) {
            float4 a = p[i];
            A2[4*i+0] = -expf(a.x) * LOG2E;
            A2[4*i+1] = -expf(a.y) * LOG2E;
            A2[4*i+2] = -expf(a.z) * LOG2E;
            A2[4*i+3] = -expf(a.w) * LOG2E;
        }
    }

    const float* usrc = (k & 1) ? xcTt : xcT;
    int pbase = (k < 2) ? l0 : (LL - 1 - l0);
    int pstep = (k < 2) ? 1 : -1;
    const float* up = usrc + ((size_t)b * LL + pbase) * DI + d;
    ptrdiff_t ustep = (ptrdiff_t)pstep * DI;

    const float4* Dt = (const float4*)(dts + ((size_t)bk * LL + l0) * RR);

    float h[16];
    #pragma unroll
    for (int i = 0; i < 16; ++i) h[i] = 0.f;
    float td = 0.f;

    __syncthreads();

    for (int lb = 0; lb < 4; ++lb) {
        float del[12];
        #pragma unroll
        for (int j = 0; j < 12; ++j) {
            int l = lb * 12 + j;
            float4 q0 = Dt[l*3+0], q1 = Dt[l*3+1], q2 = Dt[l*3+2];
            float acc = dtbv
                + q0.x*w12[0] + q0.y*w12[1] + q0.z*w12[2]  + q0.w*w12[3]
                + q1.x*w12[4] + q1.y*w12[5] + q1.z*w12[6]  + q1.w*w12[7]
                + q2.x*w12[8] + q2.y*w12[9] + q2.z*w12[10] + q2.w*w12[11];
            del[j] = softplus_f(acc);
        }
        #pragma unroll
        for (int j = 0; j < 12; ++j) {
            int l = lb * 12 + j;
            float delta = del[j];
            float u = *up; up += ustep;
            td += delta;
            float du = delta * u;
            const float4* Bl = (const float4*)&sB[l * 16];
            float4 B0 = Bl[0], B1 = Bl[1], B2 = Bl[2], B3 = Bl[3];
            h[0]  = h[0]  * fexp2(delta * A2[0])  + du * B0.x;
            h[1]  = h[1]  * fexp2(delta * A2[1])  + du * B0.y;
            h[2]  = h[2]  * fexp2(delta * A2[2])  + du * B0.z;
            h[3]  = h[3]  * fexp2(delta * A2[3])  + du * B0.w;
            h[4]  = h[4]  * fexp2(delta * A2[4])  + du * B1.x;
            h[5]  = h[5]  * fexp2(delta * A2[5])  + du * B1.y;
            h[6]  = h[6]  * fexp2(delta * A2[6])  + du * B1.z;
            h[7]  = h[7]  * fexp2(delta * A2[7])  + du * B1.w;
            h[8]  = h[8]  * fexp2(delta * A2[8])  + du * B2.x;
            h[9]  = h[9]  * fexp2(delta * A2[9])  + du * B2.y;
            h[10] = h[10] * fexp2(delta * A2[10]) + du * B2.z;
            h[11] = h[11] * fexp2(delta * A2[11]) + du * B2.w;
            h[12] = h[12] * fexp2(delta * A2[12]) + du * B3.x;
            h[13] = h[13] * fexp2(delta * A2[13]) + du * B3.y;
            h[14] = h[14] * fexp2(delta * A2[14]) + du * B3.z;
            h[15] = h[15] * fexp2(delta * A2[15]) + du * B3.w;
        }
    }

    float4* ho = (float4*)(hstin + ((size_t)(bk * CH + c) * DI + d) * NN);
    #pragma unroll
    for (int i = 0; i < 4; ++i) {
        float4 o; o.x = h[4*i]; o.y = h[4*i+1]; o.z = h[4*i+2]; o.w = h[4*i+3];
        ho[i] = o;
    }
    Tsum[(size_t)(bk * CH + c) * DI + d] = td;
}

// ---------------- combine (in-place): end-states -> incoming states
__global__ __launch_bounds__(256) void k_scan_combine(
    float* __restrict__ hstin,
    const float* __restrict__ Tsum,
    const float* __restrict__ Alogs)
{
    int t = blockIdx.x * 256 + threadIdx.x;   // B*K*DI*NN = 98304
    int n = t & 15;
    int d = (t >> 4) % DI;
    int bk = t / (DI * NN);
    int k = bk & 3;
    float A2 = -expf(Alogs[(size_t)(k * DI + d) * NN + n]) * LOG2E;
    float h = 0.f;
    for (int c = 0; c < CH; ++c) {
        size_t rb = (size_t)(bk * CH + c) * DI + d;
        float hend = hstin[rb * NN + n];
        hstin[rb * NN + n] = h;
        float St = Tsum[rb];
        h = fexp2(A2 * St) * h + hend;
    }
}

// ---------------- fat-lane pass2 (R9 structure + sequential-u via xcTt).
__global__ __launch_bounds__(384) void k_scan_pass2(
    const float* __restrict__ xcT,
    const float* __restrict__ xcTt,
    const float* __restrict__ dts,
    const float* __restrict__ Bsb,
    const float* __restrict__ Csb,
    const float* __restrict__ dtw_g,
    const float* __restrict__ dtb_g,
    const float* __restrict__ Alogs,
    const float* __restrict__ Ds_g,
    const float* __restrict__ hin,
    float* __restrict__ yk)
{
    __shared__ float sB[CLEN * 16];      // 3 KB
    __shared__ float sC[CLEN * 16];      // 3 KB
    int blk = blockIdx.x;            // bk*CH + c
    int c = blk % CH;
    int bk = blk / CH;
    int k = bk & 3, b = bk >> 2;
    int d = threadIdx.x;             // 0..383
    int l0 = c * CLEN;
    int kd = k * DI + d;

    {   // coop stage: threads 0-191 -> B, 192-383 -> C (192 float4 each)
        const float4* Bg = (const float4*)(Bsb + ((size_t)bk * LL + l0) * NN);
        const float4* Cg = (const float4*)(Csb + ((size_t)bk * LL + l0) * NN);
        if (d < 192) ((float4*)sB)[d] = Bg[d];
        else         ((float4*)sC)[d - 192] = Cg[d - 192];
    }

    float dtbv = dtb_g[kd];
    float w12[12];
    {
        const float4* p = (const float4*)(dtw_g + (size_t)kd * RR);
        float4 a0 = p[0], a1 = p[1], a2 = p[2];
        w12[0]=a0.x; w12[1]=a0.y; w12[2]=a0.z;  w12[3]=a0.w;
        w12[4]=a1.x; w12[5]=a1.y; w12[6]=a1.z;  w12[7]=a1.w;
        w12[8]=a2.x; w12[9]=a2.y; w12[10]=a2.z; w12[11]=a2.w;
    }
    float A2[16];
    {
        const float4* p = (const float4*)(Alogs + (size_t)kd * NN);
        #pragma unroll
        for (int i = 0; i < 4; ++i) {
            float4 a = p[i];
            A2[4*i+0] = -expf(a.x) * LOG2E;
            A2[4*i+1] = -expf(a.y) * LOG2E;
            A2[4*i+2] = -expf(a.z) * LOG2E;
            A2[4*i+3] = -expf(a.w) * LOG2E;
        }
    }
    float Dv = Ds_g[kd];

    const float* usrc = (k & 1) ? xcTt : xcT;
    int pbase = (k < 2) ? l0 : (LL - 1 - l0);
    int pstep = (k < 2) ? 1 : -1;
    const float* up = usrc + ((size_t)b * LL + pbase) * DI + d;
    ptrdiff_t ustep = (ptrdiff_t)pstep * DI;

    const float4* Dt = (const float4*)(dts + ((size_t)bk * LL + l0) * RR);

    float h[16];
    {
        const float4* hp = (const float4*)(hin + ((size_t)(bk * CH + c) * DI + d) * NN);
        #pragma unroll
        for (int i = 0; i < 4; ++i) {
            float4 a = hp[i];
            h[4*i] = a.x; h[4*i+1] = a.y; h[4*i+2] = a.z; h[4*i+3] = a.w;
        }
    }
    float* yc = yk + ((size_t)bk * LL + l0) * DI + d;

    __syncthreads();

    for (int lb = 0; lb < 4; ++lb) {
        float del[12];
        #pragma unroll
        for (int j = 0; j < 12; ++j) {
            int l = lb * 12 + j;
            float4 q0 = Dt[l*3+0], q1 = Dt[l*3+1], q2 = Dt[l*3+2];
            float acc = dtbv
                + q0.x*w12[0] + q0.y*w12[1] + q0.z*w12[2]  + q0.w*w12[3]
                + q1.x*w12[4] + q1.y*w12[5] + q1.z*w12[6]  + q1.w*w12[7]
                + q2.x*w12[8] + q2.y*w12[9] + q2.z*w12[10] + q2.w*w12[11];
            del[j] = softplus_f(acc);
        }
        #pragma unroll
        for (int j = 0; j < 12; ++j) {
            int l = lb * 12 + j;
            float delta = del[j];
            float u = *up; up += ustep;
            float du = delta * u;
            const float4* Bl = (const float4*)&sB[l * 16];
            float4 B0 = Bl[0], B1 = Bl[1], B2 = Bl[2], B3 = Bl[3];
            h[0]  = h[0]  * fexp2(delta * A2[0])  + du * B0.x;
            h[1]  = h[1]  * fexp2(delta * A2[1])  + du * B0.y;
            h[2]  = h[2]  * fexp2(delta * A2[2])  + du * B0.z;
            h[3]  = h[3]  * fexp2(delta * A2[3])  + du * B0.w;
            h[4]  = h[4]  * fexp2(delta * A2[4])  + du * B1.x;
            h[5]  = h[5]  * fexp2(delta * A2[5])  + du * B1.y;
            h[6]  = h[6]  * fexp2(delta * A2[6])  + du * B1.z;
            h[7]  = h[7]  * fexp2(delta * A2[7])  + du * B1.w;
            h[8]  = h[8]  * fexp2(delta * A2[8])  + du * B2.x;
            h[9]  = h[9]  * fexp2(delta * A2[9])  + du * B2.y;
            h[10] = h[10] * fexp2(delta * A2[10]) + du * B2.z;
            h[11] = h[11] * fexp2(delta * A2[11]) + du * B2.w;
            h[12] = h[12] * fexp2(delta * A2[12]) + du * B3.x;
            h[13] = h[13] * fexp2(delta * A2[13]) + du * B3.y;
            h[14] = h[14] * fexp2(delta * A2[14]) + du * B3.z;
            h[15] = h[15] * fexp2(delta * A2[15]) + du * B3.w;
            const float4* Cl = (const float4*)&sC[l * 16];
            float4 C0 = Cl[0], C1 = Cl[1], C2 = Cl[2], C3 = Cl[3];
            float y0 = h[0]*C0.x + h[1]*C0.y + h[2]*C0.z  + h[3]*C0.w;
            float y1 = h[4]*C1.x + h[5]*C1.y + h[6]*C1.z  + h[7]*C1.w;
            float y2 = h[8]*C2.x + h[9]*C2.y + h[10]*C2.z + h[11]*C2.w;
            float y3 = h[12]*C3.x + h[13]*C3.y + h[14]*C3.z + h[15]*C3.w;
            yc[(size_t)l * DI] = (y0 + y1) + (y2 + y3) + u * Dv;
        }
    }
}

// ---------------- merge (CrossMerge) + LayerNorm + gate -> bf16 gbuf
__global__ __launch_bounds__(384) void k_merge_ln_gate(
    const float* __restrict__ yk,
    const float* __restrict__ xcz,     // z at columns 384..767
    const float* __restrict__ lnw,
    const float* __restrict__ lnb,
    short* __restrict__ gbufb)
{
    int pg = blockIdx.x;            // b*LL + pos
    int b = pg / LL;
    int pos = pg % LL;
    int d = threadIdx.x;
    int pt = (pos % 48) * 48 + pos / 48;

    const float* y0 = yk + ((size_t)(b * 4 + 0) * LL + pos) * DI;
    const float* y1 = yk + ((size_t)(b * 4 + 1) * LL + pt) * DI;
    const float* y2 = yk + ((size_t)(b * 4 + 2) * LL + (LL - 1 - pos)) * DI;
    const float* y3 = yk + ((size_t)(b * 4 + 3) * LL + (LL - 1 - pt)) * DI;
    float v = y0[d] + y1[d] + y2[d] + y3[d];

    float s = v, qq = v * v;
    #pragma unroll
    for (int o = 32; o >= 1; o >>= 1) {
        s += __shfl_xor(s, o, 64);
        qq += __shfl_xor(qq, o, 64);
    }
    __shared__ float ssum[6], sqq[6];
    int lane = d & 63, w = d >> 6;
    if (lane == 0) { ssum[w] = s; sqq[w] = qq; }
    __syncthreads();
    float ts = 0.f, tq = 0.f;
    #pragma unroll
    for (int i = 0; i < 6; ++i) { ts += ssum[i]; tq += sqq[i]; }
    float mu = ts / (float)DI;
    float var = tq / (float)DI - mu * mu;
    float inv = rsqrtf(var + 1e-5f);
    float y = (v - mu) * inv * lnw[d] + lnb[d];
    float z = xcz[(size_t)pg * 768 + DI + d];
    gbufb[(size_t)pg * DI + d] = f2bf(y * z);
}

// ---------------- K6: out_proj via bf16 MFMA. K=384, tile 128l x 64o.
__global__ __launch_bounds__(256) void k_outproj_mfma(
    const short* __restrict__ gbufb,   // (B,L,384) bf16
    const short* __restrict__ owbf,    // (192,384) bf16
    float* __restrict__ out)           // (B,192,L) fp32
{
    __shared__ short sA[128 * 40];
    __shared__ short sB[64 * 40];
    int o0 = blockIdx.x * 64;
    int l0 = blockIdx.y * 128;
    int b  = blockIdx.z;
    int tid = threadIdx.x;
    int lane = tid & 63, wid = tid >> 6;
    int n = lane & 15, quad = lane >> 4;

    v4f acc[2][4];
    #pragma unroll
    for (int i = 0; i < 2; ++i)
        #pragma unroll
        for (int j = 0; j < 4; ++j) acc[i][j] = (v4f){0.f, 0.f, 0.f, 0.f};

    for (int kc = 0; kc < DI; kc += 32) {
        for (int i = tid; i < 512; i += 256) {
            int row = i >> 2, seg = i & 3;
            *(v8s*)&sA[row * 40 + seg * 8] =
                *(const v8s*)(gbufb + (size_t)(b * LL + l0 + row) * DI + kc + seg * 8);
        }
        {
            int row = tid >> 2, seg = tid & 3;
            *(v8s*)&sB[row * 40 + seg * 8] =
                *(const v8s*)(owbf + (size_t)(o0 + row) * DI + kc + seg * 8);
        }
        __syncthreads();
        v8s a0 = *(v8s*)&sA[(wid * 32 + n) * 40 + quad * 8];
        v8s a1 = *(v8s*)&sA[(wid * 32 + 16 + n) * 40 + quad * 8];
        #pragma unroll
        for (int os = 0; os < 4; ++os) {
            v8s bv = *(v8s*)&sB[(os * 16 + n) * 40 + quad * 8];
            acc[0][os] = __builtin_amdgcn_mfma_f32_16x16x32_bf16(a0, bv, acc[0][os], 0, 0, 0);
            acc[1][os] = __builtin_amdgcn_mfma_f32_16x16x32_bf16(a1, bv, acc[1][os], 0, 0, 0);
        }
        __syncthreads();
    }
    #pragma unroll
    for (int ls = 0; ls < 2; ++ls)
        #pragma unroll
        for (int os = 0; os < 4; ++os) {
            int o = o0 + os * 16 + n;
            #pragma unroll
            for (int r = 0; r < 4; ++r) {
                int l = l0 + wid * 32 + ls * 16 + quad * 4 + r;
                out[(size_t)(b * DM + o) * LL + l] = acc[ls][os][r];
            }
        }
}

extern "C" void kernel_launch(void* const* d_in, const int* in_sizes, int n_in,
                              void* d_out, int out_size, void* d_ws, size_t ws_size,
                              hipStream_t stream) {
    (void)in_sizes; (void)n_in; (void)out_size; (void)ws_size;
    const float* x      = (const float*)d_in[0];
    const float* ipw    = (const float*)d_in[1];
    const float* cw     = (const float*)d_in[2];
    const float* cb     = (const float*)d_in[3];
    const float* xpw    = (const float*)d_in[4];
    const float* dtw    = (const float*)d_in[5];
    const float* dtb    = (const float*)d_in[6];
    const float* Alogs  = (const float*)d_in[7];
    const float* Ds     = (const float*)d_in[8];
    const float* lnw    = (const float*)d_in[9];
    const float* lnb    = (const float*)d_in[10];
    const float* opw    = (const float*)d_in[11];
    float* out = (float*)d_out;

    float* wsf = (float*)d_ws;
    const size_t XCZ = (size_t)BQ * LL * 768;             //  7,077,888
    const size_t SZ  = (size_t)BQ * DI * LL;              //  3,538,944
    const size_t DTS = (size_t)BQ * KK * LL * RR;         //    442,368
    const size_t BCS = (size_t)BQ * KK * LL * NN;         //    589,824
    const size_t TSM = (size_t)BQ * KK * CH * DI;         //    294,912
    const size_t SBF = (size_t)BQ * KK * LL * DI;         // 14,155,776
    const size_t HST = (size_t)BQ * KK * CH * DI * NN;    //  4,718,592

    float* xcz   = wsf;                  // (B,L,768): xc half + gelu(z) half
    float* xcT   = xcz + XCZ;            // (B,L,384) fp32 conv output (scan u)
    float* xcTt  = xcT + SZ;             // (B,L,384) fp32, transposed row order
    float* dts   = xcTt + SZ;            // (B,K,L,R)
    float* Bsb   = dts + DTS;            // (B,K,L,N)
    float* Csb   = Bsb + BCS;            // (B,K,L,N)
    float* Tsum  = Csb + BCS;            // (B,K,CH,DI) chunk delta totals
    float* hstin = Tsum + TSM;           // (B,K,CH,DI,N)
    float* yk    = hstin + HST;          // (B,K,L,DI)
    short* xTbf  = (short*)(yk + SBF);   // (B,L,192) bf16 in_proj input
    short* wibf  = xTbf + (size_t)BQ * LL * DM;   // (768,192)
    short* owbf  = wibf + 768 * 192;              // (192,384)
    short* wpbf  = owbf + 192 * 384;              // (192,384) x_proj padded
    short* gbufb = wpbf + 192 * 384;              // (B,L,384) bf16 gate output
    // xcTbf (B*L*384 shorts) aliases yk: xcTbf dead after k_xproj_mfma; yk
    // first written by k_scan_pass2 (after).
    short* xcTbf = (short*)yk;

    k_prep_w<<<1152, 256, 0, stream>>>(ipw, opw, xpw, wibf, owbf, wpbf);
    k_prep_xT<<<BQ * 72 * 6, 256, 0, stream>>>(x, xTbf);
    k_inproj_mfma<<<dim3(12, 18, BQ), 256, 0, stream>>>(xTbf, wibf, xcz);
    k_dwconv<<<BQ * HH * 4, 384, 0, stream>>>(xcz, cw, cb, xcT, xcTt, xcTbf);
    k_xproj_mfma<<<dim3(3, 18, BQ), 256, 0, stream>>>(xcTbf, wpbf, dts, Bsb, Csb);

    k_scan_pass1<<<BQ * KK * CH, 384, 0, stream>>>(
        xcT, xcTt, dts, Bsb, dtw, dtb, Alogs, hstin, Tsum);
    k_scan_combine<<<(BQ * KK * DI * NN) / 256, 256, 0, stream>>>(
        hstin, Tsum, Alogs);
    k_scan_pass2<<<BQ * KK * CH, 384, 0, stream>>>(
        xcT, xcTt, dts, Bsb, Csb, dtw, dtb, Alogs, Ds, hstin, yk);
    k_merge_ln_gate<<<BQ * LL, 384, 0, stream>>>(yk, xcz, lnw, lnb, gbufb);

    k_outproj_mfma<<<dim3(3, 18, BQ), 256, 0, stream>>>(gbufb, owbf, out);
}

// Round 13
// 282.388 us; speedup vs baseline: 1.0050x; 1.0050x over previous
//
#include <hip/hip_runtime.h>
#include <math.h>

#define BQ 4
#define DM 192
#define DI 384
#define HH 48
#define WW 48
#define LL 2304
#define KK 4
#define NN 16
#define RR 12
#define CH 48      // chunks per sequence
#define CLEN 48    // chunk length

#define LOG2E 1.4426950408889634f
#define LN2   0.6931471805599453f

typedef short v8s __attribute__((ext_vector_type(8)));
typedef float v4f __attribute__((ext_vector_type(4)));

__device__ __forceinline__ float gelu_exact(float x) {
    return 0.5f * x * (1.0f + erff(x * 0.7071067811865476f));
}

__device__ __forceinline__ float fexp2(float x) {
    return __builtin_amdgcn_exp2f(x);
}

__device__ __forceinline__ float flog2(float x) {
    return __builtin_amdgcn_logf(x);
}

// softplus via hw exp2/log2: max(x,0) + ln2*log2(1 + 2^(-|x|*log2e))
__device__ __forceinline__ float softplus_f(float x) {
    float t = fexp2(-fabsf(x) * LOG2E);
    return fmaxf(x, 0.0f) + LN2 * flog2(1.0f + t);
}

__device__ __forceinline__ int pt_of(int p) {   // 48x48 transpose, involution
    return (p % 48) * 48 + p / 48;
}

__device__ __forceinline__ short f2bf(float x) {
    unsigned u = __float_as_uint(x);
    unsigned r = (u + 0x7FFFu + ((u >> 16) & 1u)) >> 16;
    return (short)r;
}

// ---------------- P1: cast weights to bf16. wpbf = x_proj (176,384) padded to 192 rows.
__global__ __launch_bounds__(256) void k_prep_w(const float* __restrict__ ipw,
                                                const float* __restrict__ opw,
                                                const float* __restrict__ xpw,
                                                short* __restrict__ wibf,
                                                short* __restrict__ owbf,
                                                short* __restrict__ wpbf) {
    int i = blockIdx.x * 256 + threadIdx.x;     // 1152*256 = 294912 exactly
    if (i < 147456)       wibf[i] = f2bf(ipw[i]);
    else if (i < 221184)  owbf[i - 147456] = f2bf(opw[i - 147456]);
    else if (i < 288768)  wpbf[i - 221184] = f2bf(xpw[i - 221184]);
    else                  wpbf[67584 + (i - 288768)] = 0;   // pad rows 176..191
}

// ---------------- P2: transpose-cast x (B,192,L) -> xTbf (B,L,192) bf16
__global__ __launch_bounds__(256) void k_prep_xT(const float* __restrict__ x,
                                                 short* __restrict__ xTbf) {
    __shared__ float T[32][33];
    int blk = blockIdx.x;           // (b*72 + lt)*6 + dt
    int dt = blk % 6;
    int lt = (blk / 6) % 72;
    int b  = blk / (6 * 72);
    int d0 = dt * 32, l0 = lt * 32;
    int tx = threadIdx.x & 31, ty = threadIdx.x >> 5;   // ty 0..7
    #pragma unroll
    for (int i = 0; i < 4; ++i) {
        int dd = ty + 8 * i;
        T[dd][tx] = x[(size_t)(b * DM + d0 + dd) * LL + l0 + tx];
    }
    __syncthreads();
    #pragma unroll
    for (int i = 0; i < 4; ++i) {
        int ll = ty + 8 * i;
        xTbf[(size_t)(b * LL + l0 + ll) * DM + d0 + tx] = f2bf(T[tx][ll]);
    }
}

// ---------------- K1: in_proj via bf16 MFMA. D[l][o]; o<384 -> xc, else gelu->z.
__global__ __launch_bounds__(256) void k_inproj_mfma(
    const short* __restrict__ xTbf,   // (B,L,192) bf16
    const short* __restrict__ wibf,   // (768,192) bf16
    float* __restrict__ xcz)          // (B,L,768) fp32
{
    __shared__ short sA[128 * 40];    // [l][k32], row stride 40 shorts
    __shared__ short sB[64 * 40];     // [o][k32]
    int o0 = blockIdx.x * 64;
    int l0 = blockIdx.y * 128;
    int b  = blockIdx.z;
    int tid = threadIdx.x;
    int lane = tid & 63, wid = tid >> 6;
    int n = lane & 15, quad = lane >> 4;

    v4f acc[2][4];
    #pragma unroll
    for (int i = 0; i < 2; ++i)
        #pragma unroll
        for (int j = 0; j < 4; ++j) acc[i][j] = (v4f){0.f, 0.f, 0.f, 0.f};

    for (int kc = 0; kc < 192; kc += 32) {
        for (int i = tid; i < 512; i += 256) {
            int row = i >> 2, seg = i & 3;
            *(v8s*)&sA[row * 40 + seg * 8] =
                *(const v8s*)(xTbf + (size_t)(b * LL + l0 + row) * DM + kc + seg * 8);
        }
        {
            int row = tid >> 2, seg = tid & 3;
            *(v8s*)&sB[row * 40 + seg * 8] =
                *(const v8s*)(wibf + (size_t)(o0 + row) * DM + kc + seg * 8);
        }
        __syncthreads();
        v8s a0 = *(v8s*)&sA[(wid * 32 + n) * 40 + quad * 8];
        v8s a1 = *(v8s*)&sA[(wid * 32 + 16 + n) * 40 + quad * 8];
        #pragma unroll
        for (int os = 0; os < 4; ++os) {
            v8s bv = *(v8s*)&sB[(os * 16 + n) * 40 + quad * 8];
            acc[0][os] = __builtin_amdgcn_mfma_f32_16x16x32_bf16(a0, bv, acc[0][os], 0, 0, 0);
            acc[1][os] = __builtin_amdgcn_mfma_f32_16x16x32_bf16(a1, bv, acc[1][os], 0, 0, 0);
        }
        __syncthreads();
    }
    bool zhalf = (o0 >= DI);
    #pragma unroll
    for (int ls = 0; ls < 2; ++ls)
        #pragma unroll
        for (int os = 0; os < 4; ++os) {
            int o = o0 + os * 16 + n;
            #pragma unroll
            for (int r = 0; r < 4; ++r) {
                int l = l0 + wid * 32 + ls * 16 + quad * 4 + r;
                float v = acc[ls][os][r];
                xcz[(size_t)(b * LL + l) * 768 + o] = zhalf ? gelu_exact(v) : v;
            }
        }
}

// ---------------- K2: depthwise 3x3 conv + bias + gelu, [l][c] layout.
// Writes xcT fp32 (row-major), xcTt fp32 (spatially TRANSPOSED row order:
// row' = pt(row)) and xcTbf bf16. xcTt makes the k=1/k=3 scan directions
// sequential-row walks (u-load stride +-1536B instead of +-73728B).
__global__ __launch_bounds__(384) void k_dwconv(const float* __restrict__ xcz,
                                                const float* __restrict__ cw,
                                                const float* __restrict__ cb,
                                                float* __restrict__ xcT,
                                                float* __restrict__ xcTt,
                                                short* __restrict__ xcTbf) {
    int blk = blockIdx.x;           // ((b*HH + h)*4 + seg)
    int seg = blk & 3;
    int bh = blk >> 2;
    int b = bh / HH, h = bh % HH;
    int d = threadIdx.x;
    int w0 = seg * 12;
    const float* in = xcz + (size_t)b * LL * 768 + d;
    float w9[9];
    #pragma unroll
    for (int i = 0; i < 9; ++i) w9[i] = cw[d * 9 + i];
    float bias = cb[d];
    bool hm = h > 0, hp = h < HH - 1;
    int r0 = (h - 1) * WW, r1 = h * WW, r2 = (h + 1) * WW;
    float c00, c01, c02, c10, c11, c12, c20, c21, c22;
    bool wl = (w0 > 0);
    c00 = (hm && wl) ? in[(size_t)(r0 + w0 - 1) * 768] : 0.f;
    c10 = wl ? in[(size_t)(r1 + w0 - 1) * 768] : 0.f;
    c20 = (hp && wl) ? in[(size_t)(r2 + w0 - 1) * 768] : 0.f;
    c01 = hm ? in[(size_t)(r0 + w0) * 768] : 0.f;
    c11 = in[(size_t)(r1 + w0) * 768];
    c21 = hp ? in[(size_t)(r2 + w0) * 768] : 0.f;
    c02 = hm ? in[(size_t)(r0 + w0 + 1) * 768] : 0.f;
    c12 = in[(size_t)(r1 + w0 + 1) * 768];
    c22 = hp ? in[(size_t)(r2 + w0 + 1) * 768] : 0.f;
    #pragma unroll
    for (int wi = 0; wi < 12; ++wi) {
        int w = w0 + wi;
        float s = bias
            + w9[0] * c00 + w9[1] * c01 + w9[2] * c02
            + w9[3] * c10 + w9[4] * c11 + w9[5] * c12
            + w9[6] * c20 + w9[7] * c21 + w9[8] * c22;
        float v = gelu_exact(s);
        int pos = h * WW + w;
        size_t row  = (size_t)b * LL + pos;
        size_t rowt = (size_t)b * LL + (w * 48 + h);   // pt(pos)
        xcT[row * DI + d] = v;
        xcTt[rowt * DI + d] = v;
        xcTbf[row * DI + d] = f2bf(v);
        c00 = c01; c01 = c02; c10 = c11; c11 = c12; c20 = c21; c21 = c22;
        int wn = w + 2;
        bool okw = wn < WW;
        c02 = (hm && okw) ? in[(size_t)(r0 + wn) * 768] : 0.f;
        c12 = okw ? in[(size_t)(r1 + wn) * 768] : 0.f;
        c22 = (hp && okw) ? in[(size_t)(r2 + wn) * 768] : 0.f;
    }
}

// ---------------- K3: x_proj, ALL 4 directions as ONE bf16 MFMA GEMM.
__global__ __launch_bounds__(256) void k_xproj_mfma(
    const short* __restrict__ xcTbf,  // (B,L,384) bf16
    const short* __restrict__ wpbf,   // (192,384) bf16, rows>=176 zero
    float* __restrict__ dts,
    float* __restrict__ Bsb,
    float* __restrict__ Csb)
{
    __shared__ short sA[128 * 40];
    __shared__ short sB[64 * 40];
    int o0 = blockIdx.x * 64;
    int l0 = blockIdx.y * 128;
    int b  = blockIdx.z;
    int tid = threadIdx.x;
    int lane = tid & 63, wid = tid >> 6;
    int n = lane & 15, quad = lane >> 4;

    v4f acc[2][4];
    #pragma unroll
    for (int i = 0; i < 2; ++i)
        #pragma unroll
        for (int j = 0; j < 4; ++j) acc[i][j] = (v4f){0.f, 0.f, 0.f, 0.f};

    for (int kc = 0; kc < DI; kc += 32) {
        for (int i = tid; i < 512; i += 256) {
            int row = i >> 2, seg = i & 3;
            *(v8s*)&sA[row * 40 + seg * 8] =
                *(const v8s*)(xcTbf + (size_t)(b * LL + l0 + row) * DI + kc + seg * 8);
        }
        {
            int row = tid >> 2, seg = tid & 3;
            *(v8s*)&sB[row * 40 + seg * 8] =
                *(const v8s*)(wpbf + (size_t)(o0 + row) * DI + kc + seg * 8);
        }
        __syncthreads();
        v8s a0 = *(v8s*)&sA[(wid * 32 + n) * 40 + quad * 8];
        v8s a1 = *(v8s*)&sA[(wid * 32 + 16 + n) * 40 + quad * 8];
        #pragma unroll
        for (int os = 0; os < 4; ++os) {
            v8s bv = *(v8s*)&sB[(os * 16 + n) * 40 + quad * 8];
            acc[0][os] = __builtin_amdgcn_mfma_f32_16x16x32_bf16(a0, bv, acc[0][os], 0, 0, 0);
            acc[1][os] = __builtin_amdgcn_mfma_f32_16x16x32_bf16(a1, bv, acc[1][os], 0, 0, 0);
        }
        __syncthreads();
    }
    #pragma unroll
    for (int ls = 0; ls < 2; ++ls)
        #pragma unroll
        for (int os = 0; os < 4; ++os) {
            int c_all = o0 + os * 16 + n;
            if (c_all >= 176) continue;
            int k = c_all / 44;
            int c = c_all - k * 44;
            int bk = b * 4 + k;
            #pragma unroll
            for (int r = 0; r < 4; ++r) {
                int lp = l0 + wid * 32 + ls * 16 + quad * 4 + r;
                int lk = (k == 0) ? lp
                       : (k == 1) ? pt_of(lp)
                       : (k == 2) ? (LL - 1 - lp)
                                  : (LL - 1 - pt_of(lp));
                float v = acc[ls][os][r];
                size_t base = (size_t)bk * LL + lk;
                if (c < RR)           dts[base * RR + c] = v;
                else if (c < RR + NN) Bsb[base * NN + (c - RR)] = v;
                else                  Csb[base * NN + (c - RR - NN)] = v;
            }
        }
}

// ---------------- fat-lane pass1 (R10 + I$ fix: outer lb-loop NOT unrolled).
// All prior variants fully unrolled 48 iters -> ~40KB loop body > 32KB I$;
// instruction fetch was the pipe-invariant ~75us wall. Body now ~10KB.
__global__ __launch_bounds__(384) void k_scan_pass1(
    const float* __restrict__ xcT,
    const float* __restrict__ xcTt,
    const float* __restrict__ dts,
    const float* __restrict__ Bsb,
    const float* __restrict__ dtw_g,
    const float* __restrict__ dtb_g,
    const float* __restrict__ Alogs,
    float* __restrict__ hstin,
    float* __restrict__ Tsum)
{
    __shared__ float sB[CLEN * 16];      // 3 KB, [l][n]
    int blk = blockIdx.x;            // bk*CH + c
    int c = blk % CH;
    int bk = blk / CH;
    int k = bk & 3, b = bk >> 2;
    int d = threadIdx.x;             // 0..383
    int l0 = c * CLEN;
    int kd = k * DI + d;

    {   // coop stage: 192 float4
        const float4* Bg = (const float4*)(Bsb + ((size_t)bk * LL + l0) * NN);
        if (d < 192) ((float4*)sB)[d] = Bg[d];
    }

    float dtbv = dtb_g[kd];
    float w12[12];
    {
        const float4* p = (const float4*)(dtw_g + (size_t)kd * RR);
        float4 a0 = p[0], a1 = p[1], a2 = p[2];
        w12[0]=a0.x; w12[1]=a0.y; w12[2]=a0.z;  w12[3]=a0.w;
        w12[4]=a1.x; w12[5]=a1.y; w12[6]=a1.z;  w12[7]=a1.w;
        w12[8]=a2.x; w12[9]=a2.y; w12[10]=a2.z; w12[11]=a2.w;
    }
    float A2[16];
    {
        const float4* p = (const float4*)(Alogs + (size_t)kd * NN);
        #pragma unroll
        for (int i = 0; i < 4; ++i) {
            float4 a = p[i];
            A2[4*i+0] = -expf(a.x) * LOG2E;
            A2[4*i+1] = -expf(a.y) * LOG2E;
            A2[4*i+2] = -expf(a.z) * LOG2E;
            A2[4*i+3] = -expf(a.w) * LOG2E;
        }
    }

    const float* usrc = (k & 1) ? xcTt : xcT;
    int pbase = (k < 2) ? l0 : (LL - 1 - l0);
    int pstep = (k < 2) ? 1 : -1;
    const float* up = usrc + ((size_t)b * LL + pbase) * DI + d;
    ptrdiff_t ustep = (ptrdiff_t)pstep * DI;

    const float4* Dt = (const float4*)(dts + ((size_t)bk * LL + l0) * RR);

    float h[16];
    #pragma unroll
    for (int i = 0; i < 16; ++i) h[i] = 0.f;
    float td = 0.f;

    __syncthreads();

    #pragma unroll 1
    for (int lb = 0; lb < 4; ++lb) {
        float del[12];
        #pragma unroll
        for (int j = 0; j < 12; ++j) {
            int l = lb * 12 + j;
            float4 q0 = Dt[l*3+0], q1 = Dt[l*3+1], q2 = Dt[l*3+2];
            float acc = dtbv
                + q0.x*w12[0] + q0.y*w12[1] + q0.z*w12[2]  + q0.w*w12[3]
                + q1.x*w12[4] + q1.y*w12[5] + q1.z*w12[6]  + q1.w*w12[7]
                + q2.x*w12[8] + q2.y*w12[9] + q2.z*w12[10] + q2.w*w12[11];
            del[j] = softplus_f(acc);
        }
        #pragma unroll
        for (int j = 0; j < 12; ++j) {
            int l = lb * 12 + j;
            float delta = del[j];
            float u = *up; up += ustep;
            td += delta;
            float du = delta * u;
            const float4* Bl = (const float4*)&sB[l * 16];
            float4 B0 = Bl[0], B1 = Bl[1], B2 = Bl[2], B3 = Bl[3];
            h[0]  = h[0]  * fexp2(delta * A2[0])  + du * B0.x;
            h[1]  = h[1]  * fexp2(delta * A2[1])  + du * B0.y;
            h[2]  = h[2]  * fexp2(delta * A2[2])  + du * B0.z;
            h[3]  = h[3]  * fexp2(delta * A2[3])  + du * B0.w;
            h[4]  = h[4]  * fexp2(delta * A2[4])  + du * B1.x;
            h[5]  = h[5]  * fexp2(delta * A2[5])  + du * B1.y;
            h[6]  = h[6]  * fexp2(delta * A2[6])  + du * B1.z;
            h[7]  = h[7]  * fexp2(delta * A2[7])  + du * B1.w;
            h[8]  = h[8]  * fexp2(delta * A2[8])  + du * B2.x;
            h[9]  = h[9]  * fexp2(delta * A2[9])  + du * B2.y;
            h[10] = h[10] * fexp2(delta * A2[10]) + du * B2.z;
            h[11] = h[11] * fexp2(delta * A2[11]) + du * B2.w;
            h[12] = h[12] * fexp2(delta * A2[12]) + du * B3.x;
            h[13] = h[13] * fexp2(delta * A2[13]) + du * B3.y;
            h[14] = h[14] * fexp2(delta * A2[14]) + du * B3.z;
            h[15] = h[15] * fexp2(delta * A2[15]) + du * B3.w;
        }
    }

    float4* ho = (float4*)(hstin + ((size_t)(bk * CH + c) * DI + d) * NN);
    #pragma unroll
    for (int i = 0; i < 4; ++i) {
        float4 o; o.x = h[4*i]; o.y = h[4*i+1]; o.z = h[4*i+2]; o.w = h[4*i+3];
        ho[i] = o;
    }
    Tsum[(size_t)(bk * CH + c) * DI + d] = td;
}

// ---------------- combine (in-place): end-states -> incoming states
__global__ __launch_bounds__(256) void k_scan_combine(
    float* __restrict__ hstin,
    const float* __restrict__ Tsum,
    const float* __restrict__ Alogs)
{
    int t = blockIdx.x * 256 + threadIdx.x;   // B*K*DI*NN = 98304
    int n = t & 15;
    int d = (t >> 4) % DI;
    int bk = t / (DI * NN);
    int k = bk & 3;
    float A2 = -expf(Alogs[(size_t)(k * DI + d) * NN + n]) * LOG2E;
    float h = 0.f;
    for (int c = 0; c < CH; ++c) {
        size_t rb = (size_t)(bk * CH + c) * DI + d;
        float hend = hstin[rb * NN + n];
        hstin[rb * NN + n] = h;
        float St = Tsum[rb];
        h = fexp2(A2 * St) * h + hend;
    }
}

// ---------------- fat-lane pass2 (R10 + I$ fix: outer lb-loop NOT unrolled).
__global__ __launch_bounds__(384) void k_scan_pass2(
    const float* __restrict__ xcT,
    const float* __restrict__ xcTt,
    const float* __restrict__ dts,
    const float* __restrict__ Bsb,
    const float* __restrict__ Csb,
    const float* __restrict__ dtw_g,
    const float* __restrict__ dtb_g,
    const float* __restrict__ Alogs,
    const float* __restrict__ Ds_g,
    const float* __restrict__ hin,
    float* __restrict__ yk)
{
    __shared__ float sB[CLEN * 16];      // 3 KB
    __shared__ float sC[CLEN * 16];      // 3 KB
    int blk = blockIdx.x;            // bk*CH + c
    int c = blk % CH;
    int bk = blk / CH;
    int k = bk & 3, b = bk >> 2;
    int d = threadIdx.x;             // 0..383
    int l0 = c * CLEN;
    int kd = k * DI + d;

    {   // coop stage: threads 0-191 -> B, 192-383 -> C (192 float4 each)
        const float4* Bg = (const float4*)(Bsb + ((size_t)bk * LL + l0) * NN);
        const float4* Cg = (const float4*)(Csb + ((size_t)bk * LL + l0) * NN);
        if (d < 192) ((float4*)sB)[d] = Bg[d];
        else         ((float4*)sC)[d - 192] = Cg[d - 192];
    }

    float dtbv = dtb_g[kd];
    float w12[12];
    {
        const float4* p = (const float4*)(dtw_g + (size_t)kd * RR);
        float4 a0 = p[0], a1 = p[1], a2 = p[2];
        w12[0]=a0.x; w12[1]=a0.y; w12[2]=a0.z;  w12[3]=a0.w;
        w12[4]=a1.x; w12[5]=a1.y; w12[6]=a1.z;  w12[7]=a1.w;
        w12[8]=a2.x; w12[9]=a2.y; w12[10]=a2.z; w12[11]=a2.w;
    }
    float A2[16];
    {
        const float4* p = (const float4*)(Alogs + (size_t)kd * NN);
        #pragma unroll
        for (int i = 0; i < 4; ++i) {
            float4 a = p[i];
            A2[4*i+0] = -expf(a.x) * LOG2E;
            A2[4*i+1] = -expf(a.y) * LOG2E;
            A2[4*i+2] = -expf(a.z) * LOG2E;
            A2[4*i+3] = -expf(a.w) * LOG2E;
        }
    }
    float Dv = Ds_g[kd];

    const float* usrc = (k & 1) ? xcTt : xcT;
    int pbase = (k < 2) ? l0 : (LL - 1 - l0);
    int pstep = (k < 2) ? 1 : -1;
    const float* up = usrc + ((size_t)b * LL + pbase) * DI + d;
    ptrdiff_t ustep = (ptrdiff_t)pstep * DI;

    const float4* Dt = (const float4*)(dts + ((size_t)bk * LL + l0) * RR);

    float h[16];
    {
        const float4* hp = (const float4*)(hin + ((size_t)(bk * CH + c) * DI + d) * NN);
        #pragma unroll
        for (int i = 0; i < 4; ++i) {
            float4 a = hp[i];
            h[4*i] = a.x; h[4*i+1] = a.y; h[4*i+2] = a.z; h[4*i+3] = a.w;
        }
    }
    float* yc = yk + ((size_t)bk * LL + l0) * DI + d;

    __syncthreads();

    #pragma unroll 1
    for (int lb = 0; lb < 4; ++lb) {
        float del[12];
        #pragma unroll
        for (int j = 0; j < 12; ++j) {
            int l = lb * 12 + j;
            float4 q0 = Dt[l*3+0], q1 = Dt[l*3+1], q2 = Dt[l*3+2];
            float acc = dtbv
                + q0.x*w12[0] + q0.y*w12[1] + q0.z*w12[2]  + q0.w*w12[3]
                + q1.x*w12[4] + q1.y*w12[5] + q1.z*w12[6]  + q1.w*w12[7]
                + q2.x*w12[8] + q2.y*w12[9] + q2.z*w12[10] + q2.w*w12[11];
            del[j] = softplus_f(acc);
        }
        #pragma unroll
        for (int j = 0; j < 12; ++j) {
            int l = lb * 12 + j;
            float delta = del[j];
            float u = *up; up += ustep;
            float du = delta * u;
            const float4* Bl = (const float4*)&sB[l * 16];
            float4 B0 = Bl[0], B1 = Bl[1], B2 = Bl[2], B3 = Bl[3];
            h[0]  = h[0]  * fexp2(delta * A2[0])  + du * B0.x;
            h[1]  = h[1]  * fexp2(delta * A2[1])  + du * B0.y;
            h[2]  = h[2]  * fexp2(delta * A2[2])  + du * B0.z;
            h[3]  = h[3]  * fexp2(delta * A2[3])  + du * B0.w;
            h[4]  = h[4]  * fexp2(delta * A2[4])  + du * B1.x;
            h[5]  = h[5]  * fexp2(delta * A2[5])  + du * B1.y;
            h[6]  = h[6]  * fexp2(delta * A2[6])  + du * B1.z;
            h[7]  = h[7]  * fexp2(delta * A2[7])  + du * B1.w;
            h[8]  = h[8]  * fexp2(delta * A2[8])  + du * B2.x;
            h[9]  = h[9]  * fexp2(delta * A2[9])  + du * B2.y;
            h[10] = h[10] * fexp2(delta * A2[10]) + du * B2.z;
            h[11] = h[11] * fexp2(delta * A2[11]) + du * B2.w;
            h[12] = h[12] * fexp2(delta * A2[12]) + du * B3.x;
            h[13] = h[13] * fexp2(delta * A2[13]) + du * B3.y;
            h[14] = h[14] * fexp2(delta * A2[14]) + du * B3.z;
            h[15] = h[15] * fexp2(delta * A2[15]) + du * B3.w;
            const float4* Cl = (const float4*)&sC[l * 16];
            float4 C0 = Cl[0], C1 = Cl[1], C2 = Cl[2], C3 = Cl[3];
            float y0 = h[0]*C0.x + h[1]*C0.y + h[2]*C0.z  + h[3]*C0.w;
            float y1 = h[4]*C1.x + h[5]*C1.y + h[6]*C1.z  + h[7]*C1.w;
            float y2 = h[8]*C2.x + h[9]*C2.y + h[10]*C2.z + h[11]*C2.w;
            float y3 = h[12]*C3.x + h[13]*C3.y + h[14]*C3.z + h[15]*C3.w;
            yc[(size_t)l * DI] = (y0 + y1) + (y2 + y3) + u * Dv;
        }
    }
}

// ---------------- merge (CrossMerge) + LayerNorm + gate -> bf16 gbuf
__global__ __launch_bounds__(384) void k_merge_ln_gate(
    const float* __restrict__ yk,
    const float* __restrict__ xcz,     // z at columns 384..767
    const float* __restrict__ lnw,
    const float* __restrict__ lnb,
    short* __restrict__ gbufb)
{
    int pg = blockIdx.x;            // b*LL + pos
    int b = pg / LL;
    int pos = pg % LL;
    int d = threadIdx.x;
    int pt = (pos % 48) * 48 + pos / 48;

    const float* y0 = yk + ((size_t)(b * 4 + 0) * LL + pos) * DI;
    const float* y1 = yk + ((size_t)(b * 4 + 1) * LL + pt) * DI;
    const float* y2 = yk + ((size_t)(b * 4 + 2) * LL + (LL - 1 - pos)) * DI;
    const float* y3 = yk + ((size_t)(b * 4 + 3) * LL + (LL - 1 - pt)) * DI;
    float v = y0[d] + y1[d] + y2[d] + y3[d];

    float s = v, qq = v * v;
    #pragma unroll
    for (int o = 32; o >= 1; o >>= 1) {
        s += __shfl_xor(s, o, 64);
        qq += __shfl_xor(qq, o, 64);
    }
    __shared__ float ssum[6], sqq[6];
    int lane = d & 63, w = d >> 6;
    if (lane == 0) { ssum[w] = s; sqq[w] = qq; }
    __syncthreads();
    float ts = 0.f, tq = 0.f;
    #pragma unroll
    for (int i = 0; i < 6; ++i) { ts += ssum[i]; tq += sqq[i]; }
    float mu = ts / (float)DI;
    float var = tq / (float)DI - mu * mu;
    float inv = rsqrtf(var + 1e-5f);
    float y = (v - mu) * inv * lnw[d] + lnb[d];
    float z = xcz[(size_t)pg * 768 + DI + d];
    gbufb[(size_t)pg * DI + d] = f2bf(y * z);
}

// ---------------- K6: out_proj via bf16 MFMA. K=384, tile 128l x 64o.
__global__ __launch_bounds__(256) void k_outproj_mfma(
    const short* __restrict__ gbufb,   // (B,L,384) bf16
    const short* __restrict__ owbf,    // (192,384) bf16
    float* __restrict__ out)           // (B,192,L) fp32
{
    __shared__ short sA[128 * 40];
    __shared__ short sB[64 * 40];
    int o0 = blockIdx.x * 64;
    int l0 = blockIdx.y * 128;
    int b  = blockIdx.z;
    int tid = threadIdx.x;
    int lane = tid & 63, wid = tid >> 6;
    int n = lane & 15, quad = lane >> 4;

    v4f acc[2][4];
    #pragma unroll
    for (int i = 0; i < 2; ++i)
        #pragma unroll
        for (int j = 0; j < 4; ++j) acc[i][j] = (v4f){0.f, 0.f, 0.f, 0.f};

    for (int kc = 0; kc < DI; kc += 32) {
        for (int i = tid; i < 512; i += 256) {
            int row = i >> 2, seg = i & 3;
            *(v8s*)&sA[row * 40 + seg * 8] =
                *(const v8s*)(gbufb + (size_t)(b * LL + l0 + row) * DI + kc + seg * 8);
        }
        {
            int row = tid >> 2, seg = tid & 3;
            *(v8s*)&sB[row * 40 + seg * 8] =
                *(const v8s*)(owbf + (size_t)(o0 + row) * DI + kc + seg * 8);
        }
        __syncthreads();
        v8s a0 = *(v8s*)&sA[(wid * 32 + n) * 40 + quad * 8];
        v8s a1 = *(v8s*)&sA[(wid * 32 + 16 + n) * 40 + quad * 8];
        #pragma unroll
        for (int os = 0; os < 4; ++os) {
            v8s bv = *(v8s*)&sB[(os * 16 + n) * 40 + quad * 8];
            acc[0][os] = __builtin_amdgcn_mfma_f32_16x16x32_bf16(a0, bv, acc[0][os], 0, 0, 0);
            acc[1][os] = __builtin_amdgcn_mfma_f32_16x16x32_bf16(a1, bv, acc[1][os], 0, 0, 0);
        }
        __syncthreads();
    }
    #pragma unroll
    for (int ls = 0; ls < 2; ++ls)
        #pragma unroll
        for (int os = 0; os < 4; ++os) {
            int o = o0 + os * 16 + n;
            #pragma unroll
            for (int r = 0; r < 4; ++r) {
                int l = l0 + wid * 32 + ls * 16 + quad * 4 + r;
                out[(size_t)(b * DM + o) * LL + l] = acc[ls][os][r];
            }
        }
}

extern "C" void kernel_launch(void* const* d_in, const int* in_sizes, int n_in,
                              void* d_out, int out_size, void* d_ws, size_t ws_size,
                              hipStream_t stream) {
    (void)in_sizes; (void)n_in; (void)out_size; (void)ws_size;
    const float* x      = (const float*)d_in[0];
    const float* ipw    = (const float*)d_in[1];
    const float* cw     = (const float*)d_in[2];
    const float* cb     = (const float*)d_in[3];
    const float* xpw    = (const float*)d_in[4];
    const float* dtw    = (const float*)d_in[5];
    const float* dtb    = (const float*)d_in[6];
    const float* Alogs  = (const float*)d_in[7];
    const float* Ds     = (const float*)d_in[8];
    const float* lnw    = (const float*)d_in[9];
    const float* lnb    = (const float*)d_in[10];
    const float* opw    = (const float*)d_in[11];
    float* out = (float*)d_out;

    float* wsf = (float*)d_ws;
    const size_t XCZ = (size_t)BQ * LL * 768;             //  7,077,888
    const size_t SZ  = (size_t)BQ * DI * LL;              //  3,538,944
    const size_t DTS = (size_t)BQ * KK * LL * RR;         //    442,368
    const size_t BCS = (size_t)BQ * KK * LL * NN;         //    589,824
    const size_t TSM = (size_t)BQ * KK * CH * DI;         //    294,912
    const size_t SBF = (size_t)BQ * KK * LL * DI;         // 14,155,776
    const size_t HST = (size_t)BQ * KK * CH * DI * NN;    //  4,718,592

    float* xcz   = wsf;                  // (B,L,768): xc half + gelu(z) half
    float* xcT   = xcz + XCZ;            // (B,L,384) fp32 conv output (scan u)
    float* xcTt  = xcT + SZ;             // (B,L,384) fp32, transposed row order
    float* dts   = xcTt + SZ;            // (B,K,L,R)
    float* Bsb   = dts + DTS;            // (B,K,L,N)
    float* Csb   = Bsb + BCS;            // (B,K,L,N)
    float* Tsum  = Csb + BCS;            // (B,K,CH,DI) chunk delta totals
    float* hstin = Tsum + TSM;           // (B,K,CH,DI,N)
    float* yk    = hstin + HST;          // (B,K,L,DI)
    short* xTbf  = (short*)(yk + SBF);   // (B,L,192) bf16 in_proj input
    short* wibf  = xTbf + (size_t)BQ * LL * DM;   // (768,192)
    short* owbf  = wibf + 768 * 192;              // (192,384)
    short* wpbf  = owbf + 192 * 384;              // (192,384) x_proj padded
    short* gbufb = wpbf + 192 * 384;              // (B,L,384) bf16 gate output
    // xcTbf (B*L*384 shorts) aliases yk: xcTbf dead after k_xproj_mfma; yk
    // first written by k_scan_pass2 (after).
    short* xcTbf = (short*)yk;

    k_prep_w<<<1152, 256, 0, stream>>>(ipw, opw, xpw, wibf, owbf, wpbf);
    k_prep_xT<<<BQ * 72 * 6, 256, 0, stream>>>(x, xTbf);
    k_inproj_mfma<<<dim3(12, 18, BQ), 256, 0, stream>>>(xTbf, wibf, xcz);
    k_dwconv<<<BQ * HH * 4, 384, 0, stream>>>(xcz, cw, cb, xcT, xcTt, xcTbf);
    k_xproj_mfma<<<dim3(3, 18, BQ), 256, 0, stream>>>(xcTbf, wpbf, dts, Bsb, Csb);

    k_scan_pass1<<<BQ * KK * CH, 384, 0, stream>>>(
        xcT, xcTt, dts, Bsb, dtw, dtb, Alogs, hstin, Tsum);
    k_scan_combine<<<(BQ * KK * DI * NN) / 256, 256, 0, stream>>>(
        hstin, Tsum, Alogs);
    k_scan_pass2<<<BQ * KK * CH, 384, 0, stream>>>(
        xcT, xcTt, dts, Bsb, Csb, dtw, dtb, Alogs, Ds, hstin, yk);
    k_merge_ln_gate<<<BQ * LL, 384, 0, stream>>>(yk, xcz, lnw, lnb, gbufb);

    k_outproj_mfma<<<dim3(3, 18, BQ), 256, 0, stream>>>(gbufb, owbf, out);
}

// Round 14
// 280.084 us; speedup vs baseline: 1.0132x; 1.0082x over previous
//
#include <hip/hip_runtime.h>
#include <math.h>

#define BQ 4
#define DM 192
#define DI 384
#define HH 48
#define WW 48
#define LL 2304
#define KK 4
#define NN 16
#define RR 12
#define CH 96      // chunks per sequence (R14: 2x wave supply)
#define CLEN 24    // chunk length

#define LOG2E 1.4426950408889634f
#define LN2   0.6931471805599453f

typedef short v8s __attribute__((ext_vector_type(8)));
typedef float v4f __attribute__((ext_vector_type(4)));

__device__ __forceinline__ float gelu_exact(float x) {
    return 0.5f * x * (1.0f + erff(x * 0.7071067811865476f));
}

__device__ __forceinline__ float fexp2(float x) {
    return __builtin_amdgcn_exp2f(x);
}

__device__ __forceinline__ float flog2(float x) {
    return __builtin_amdgcn_logf(x);
}

// softplus via hw exp2/log2: max(x,0) + ln2*log2(1 + 2^(-|x|*log2e))
__device__ __forceinline__ float softplus_f(float x) {
    float t = fexp2(-fabsf(x) * LOG2E);
    return fmaxf(x, 0.0f) + LN2 * flog2(1.0f + t);
}

__device__ __forceinline__ int pt_of(int p) {   // 48x48 transpose, involution
    return (p % 48) * 48 + p / 48;
}

__device__ __forceinline__ short f2bf(float x) {
    unsigned u = __float_as_uint(x);
    unsigned r = (u + 0x7FFFu + ((u >> 16) & 1u)) >> 16;
    return (short)r;
}

// ---------------- P1: cast weights to bf16. wpbf = x_proj (176,384) padded to 192 rows.
__global__ __launch_bounds__(256) void k_prep_w(const float* __restrict__ ipw,
                                                const float* __restrict__ opw,
                                                const float* __restrict__ xpw,
                                                short* __restrict__ wibf,
                                                short* __restrict__ owbf,
                                                short* __restrict__ wpbf) {
    int i = blockIdx.x * 256 + threadIdx.x;     // 1152*256 = 294912 exactly
    if (i < 147456)       wibf[i] = f2bf(ipw[i]);
    else if (i < 221184)  owbf[i - 147456] = f2bf(opw[i - 147456]);
    else if (i < 288768)  wpbf[i - 221184] = f2bf(xpw[i - 221184]);
    else                  wpbf[67584 + (i - 288768)] = 0;   // pad rows 176..191
}

// ---------------- P2: transpose-cast x (B,192,L) -> xTbf (B,L,192) bf16
__global__ __launch_bounds__(256) void k_prep_xT(const float* __restrict__ x,
                                                 short* __restrict__ xTbf) {
    __shared__ float T[32][33];
    int blk = blockIdx.x;           // (b*72 + lt)*6 + dt
    int dt = blk % 6;
    int lt = (blk / 6) % 72;
    int b  = blk / (6 * 72);
    int d0 = dt * 32, l0 = lt * 32;
    int tx = threadIdx.x & 31, ty = threadIdx.x >> 5;   // ty 0..7
    #pragma unroll
    for (int i = 0; i < 4; ++i) {
        int dd = ty + 8 * i;
        T[dd][tx] = x[(size_t)(b * DM + d0 + dd) * LL + l0 + tx];
    }
    __syncthreads();
    #pragma unroll
    for (int i = 0; i < 4; ++i) {
        int ll = ty + 8 * i;
        xTbf[(size_t)(b * LL + l0 + ll) * DM + d0 + tx] = f2bf(T[tx][ll]);
    }
}

// ---------------- K1: in_proj via bf16 MFMA. D[l][o]; o<384 -> xc, else gelu->z.
__global__ __launch_bounds__(256) void k_inproj_mfma(
    const short* __restrict__ xTbf,   // (B,L,192) bf16
    const short* __restrict__ wibf,   // (768,192) bf16
    float* __restrict__ xcz)          // (B,L,768) fp32
{
    __shared__ short sA[128 * 40];    // [l][k32], row stride 40 shorts
    __shared__ short sB[64 * 40];     // [o][k32]
    int o0 = blockIdx.x * 64;
    int l0 = blockIdx.y * 128;
    int b  = blockIdx.z;
    int tid = threadIdx.x;
    int lane = tid & 63, wid = tid >> 6;
    int n = lane & 15, quad = lane >> 4;

    v4f acc[2][4];
    #pragma unroll
    for (int i = 0; i < 2; ++i)
        #pragma unroll
        for (int j = 0; j < 4; ++j) acc[i][j] = (v4f){0.f, 0.f, 0.f, 0.f};

    for (int kc = 0; kc < 192; kc += 32) {
        for (int i = tid; i < 512; i += 256) {
            int row = i >> 2, seg = i & 3;
            *(v8s*)&sA[row * 40 + seg * 8] =
                *(const v8s*)(xTbf + (size_t)(b * LL + l0 + row) * DM + kc + seg * 8);
        }
        {
            int row = tid >> 2, seg = tid & 3;
            *(v8s*)&sB[row * 40 + seg * 8] =
                *(const v8s*)(wibf + (size_t)(o0 + row) * DM + kc + seg * 8);
        }
        __syncthreads();
        v8s a0 = *(v8s*)&sA[(wid * 32 + n) * 40 + quad * 8];
        v8s a1 = *(v8s*)&sA[(wid * 32 + 16 + n) * 40 + quad * 8];
        #pragma unroll
        for (int os = 0; os < 4; ++os) {
            v8s bv = *(v8s*)&sB[(os * 16 + n) * 40 + quad * 8];
            acc[0][os] = __builtin_amdgcn_mfma_f32_16x16x32_bf16(a0, bv, acc[0][os], 0, 0, 0);
            acc[1][os] = __builtin_amdgcn_mfma_f32_16x16x32_bf16(a1, bv, acc[1][os], 0, 0, 0);
        }
        __syncthreads();
    }
    bool zhalf = (o0 >= DI);
    #pragma unroll
    for (int ls = 0; ls < 2; ++ls)
        #pragma unroll
        for (int os = 0; os < 4; ++os) {
            int o = o0 + os * 16 + n;
            #pragma unroll
            for (int r = 0; r < 4; ++r) {
                int l = l0 + wid * 32 + ls * 16 + quad * 4 + r;
                float v = acc[ls][os][r];
                xcz[(size_t)(b * LL + l) * 768 + o] = zhalf ? gelu_exact(v) : v;
            }
        }
}

// ---------------- K2: depthwise 3x3 conv + bias + gelu, [l][c] layout.
// Writes xcT fp32 (row-major), xcTt fp32 (transposed row order) and xcTbf bf16.
__global__ __launch_bounds__(384) void k_dwconv(const float* __restrict__ xcz,
                                                const float* __restrict__ cw,
                                                const float* __restrict__ cb,
                                                float* __restrict__ xcT,
                                                float* __restrict__ xcTt,
                                                short* __restrict__ xcTbf) {
    int blk = blockIdx.x;           // ((b*HH + h)*4 + seg)
    int seg = blk & 3;
    int bh = blk >> 2;
    int b = bh / HH, h = bh % HH;
    int d = threadIdx.x;
    int w0 = seg * 12;
    const float* in = xcz + (size_t)b * LL * 768 + d;
    float w9[9];
    #pragma unroll
    for (int i = 0; i < 9; ++i) w9[i] = cw[d * 9 + i];
    float bias = cb[d];
    bool hm = h > 0, hp = h < HH - 1;
    int r0 = (h - 1) * WW, r1 = h * WW, r2 = (h + 1) * WW;
    float c00, c01, c02, c10, c11, c12, c20, c21, c22;
    bool wl = (w0 > 0);
    c00 = (hm && wl) ? in[(size_t)(r0 + w0 - 1) * 768] : 0.f;
    c10 = wl ? in[(size_t)(r1 + w0 - 1) * 768] : 0.f;
    c20 = (hp && wl) ? in[(size_t)(r2 + w0 - 1) * 768] : 0.f;
    c01 = hm ? in[(size_t)(r0 + w0) * 768] : 0.f;
    c11 = in[(size_t)(r1 + w0) * 768];
    c21 = hp ? in[(size_t)(r2 + w0) * 768] : 0.f;
    c02 = hm ? in[(size_t)(r0 + w0 + 1) * 768] : 0.f;
    c12 = in[(size_t)(r1 + w0 + 1) * 768];
    c22 = hp ? in[(size_t)(r2 + w0 + 1) * 768] : 0.f;
    #pragma unroll
    for (int wi = 0; wi < 12; ++wi) {
        int w = w0 + wi;
        float s = bias
            + w9[0] * c00 + w9[1] * c01 + w9[2] * c02
            + w9[3] * c10 + w9[4] * c11 + w9[5] * c12
            + w9[6] * c20 + w9[7] * c21 + w9[8] * c22;
        float v = gelu_exact(s);
        int pos = h * WW + w;
        size_t row  = (size_t)b * LL + pos;
        size_t rowt = (size_t)b * LL + (w * 48 + h);   // pt(pos)
        xcT[row * DI + d] = v;
        xcTt[rowt * DI + d] = v;
        xcTbf[row * DI + d] = f2bf(v);
        c00 = c01; c01 = c02; c10 = c11; c11 = c12; c20 = c21; c21 = c22;
        int wn = w + 2;
        bool okw = wn < WW;
        c02 = (hm && okw) ? in[(size_t)(r0 + wn) * 768] : 0.f;
        c12 = okw ? in[(size_t)(r1 + wn) * 768] : 0.f;
        c22 = (hp && okw) ? in[(size_t)(r2 + wn) * 768] : 0.f;
    }
}

// ---------------- K3: x_proj, ALL 4 directions as ONE bf16 MFMA GEMM.
__global__ __launch_bounds__(256) void k_xproj_mfma(
    const short* __restrict__ xcTbf,  // (B,L,384) bf16
    const short* __restrict__ wpbf,   // (192,384) bf16, rows>=176 zero
    float* __restrict__ dts,
    float* __restrict__ Bsb,
    float* __restrict__ Csb)
{
    __shared__ short sA[128 * 40];
    __shared__ short sB[64 * 40];
    int o0 = blockIdx.x * 64;
    int l0 = blockIdx.y * 128;
    int b  = blockIdx.z;
    int tid = threadIdx.x;
    int lane = tid & 63, wid = tid >> 6;
    int n = lane & 15, quad = lane >> 4;

    v4f acc[2][4];
    #pragma unroll
    for (int i = 0; i < 2; ++i)
        #pragma unroll
        for (int j = 0; j < 4; ++j) acc[i][j] = (v4f){0.f, 0.f, 0.f, 0.f};

    for (int kc = 0; kc < DI; kc += 32) {
        for (int i = tid; i < 512; i += 256) {
            int row = i >> 2, seg = i & 3;
            *(v8s*)&sA[row * 40 + seg * 8] =
                *(const v8s*)(xcTbf + (size_t)(b * LL + l0 + row) * DI + kc + seg * 8);
        }
        {
            int row = tid >> 2, seg = tid & 3;
            *(v8s*)&sB[row * 40 + seg * 8] =
                *(const v8s*)(wpbf + (size_t)(o0 + row) * DI + kc + seg * 8);
        }
        __syncthreads();
        v8s a0 = *(v8s*)&sA[(wid * 32 + n) * 40 + quad * 8];
        v8s a1 = *(v8s*)&sA[(wid * 32 + 16 + n) * 40 + quad * 8];
        #pragma unroll
        for (int os = 0; os < 4; ++os) {
            v8s bv = *(v8s*)&sB[(os * 16 + n) * 40 + quad * 8];
            acc[0][os] = __builtin_amdgcn_mfma_f32_16x16x32_bf16(a0, bv, acc[0][os], 0, 0, 0);
            acc[1][os] = __builtin_amdgcn_mfma_f32_16x16x32_bf16(a1, bv, acc[1][os], 0, 0, 0);
        }
        __syncthreads();
    }
    #pragma unroll
    for (int ls = 0; ls < 2; ++ls)
        #pragma unroll
        for (int os = 0; os < 4; ++os) {
            int c_all = o0 + os * 16 + n;
            if (c_all >= 176) continue;
            int k = c_all / 44;
            int c = c_all - k * 44;
            int bk = b * 4 + k;
            #pragma unroll
            for (int r = 0; r < 4; ++r) {
                int lp = l0 + wid * 32 + ls * 16 + quad * 4 + r;
                int lk = (k == 0) ? lp
                       : (k == 1) ? pt_of(lp)
                       : (k == 2) ? (LL - 1 - lp)
                                  : (LL - 1 - pt_of(lp));
                float v = acc[ls][os][r];
                size_t base = (size_t)bk * LL + lk;
                if (c < RR)           dts[base * RR + c] = v;
                else if (c < RR + NN) Bsb[base * NN + (c - RR)] = v;
                else                  Csb[base * NN + (c - RR - NN)] = v;
            }
        }
}

// ---------------- fat-lane pass1 (R14: CH=96, 192-thread d-half blocks).
// Clean max-TLP test: 3072 blocks x 3 waves = ~32 waves/CU (vs 18 before),
// same per-thread code as R13 (VGPR ~40, no uu batching).
__global__ __launch_bounds__(192) void k_scan_pass1(
    const float* __restrict__ xcT,
    const float* __restrict__ xcTt,
    const float* __restrict__ dts,
    const float* __restrict__ Bsb,
    const float* __restrict__ dtw_g,
    const float* __restrict__ dtb_g,
    const float* __restrict__ Alogs,
    float* __restrict__ hstin,
    float* __restrict__ Tsum)
{
    __shared__ float sB[CLEN * 16];      // 1.5 KB, [l][n]
    int blk = blockIdx.x;            // ((bk*CH + c)*2 + dh)
    int dh = blk & 1;
    int t2 = blk >> 1;
    int c = t2 % CH;
    int bk = t2 / CH;
    int k = bk & 3, b = bk >> 2;
    int tid = threadIdx.x;           // 0..191
    int d = dh * 192 + tid;
    int l0 = c * CLEN;
    int kd = k * DI + d;

    {   // coop stage: CLEN*16 floats = 96 float4
        const float4* Bg = (const float4*)(Bsb + ((size_t)bk * LL + l0) * NN);
        if (tid < 96) ((float4*)sB)[tid] = Bg[tid];
    }

    float dtbv = dtb_g[kd];
    float w12[12];
    {
        const float4* p = (const float4*)(dtw_g + (size_t)kd * RR);
        float4 a0 = p[0], a1 = p[1], a2 = p[2];
        w12[0]=a0.x; w12[1]=a0.y; w12[2]=a0.z;  w12[3]=a0.w;
        w12[4]=a1.x; w12[5]=a1.y; w12[6]=a1.z;  w12[7]=a1.w;
        w12[8]=a2.x; w12[9]=a2.y; w12[10]=a2.z; w12[11]=a2.w;
    }
    float A2[16];
    {
        const float4* p = (const float4*)(Alogs + (size_t)kd * NN);
        #pragma unroll
        for (int i = 0; i < 4; ++i) {
            float4 a = p[i];
            A2[4*i+0] = -expf(a.x) * LOG2E;
            A2[4*i+1] = -expf(a.y) * LOG2E;
            A2[4*i+2] = -expf(a.z) * LOG2E;
            A2[4*i+3] = -expf(a.w) * LOG2E;
        }
    }

    const float* usrc = (k & 1) ? xcTt : xcT;
    int pbase = (k < 2) ? l0 : (LL - 1 - l0);
    int pstep = (k < 2) ? 1 : -1;
    const float* up = usrc + ((size_t)b * LL + pbase) * DI + d;
    ptrdiff_t ustep = (ptrdiff_t)pstep * DI;

    const float4* Dt = (const float4*)(dts + ((size_t)bk * LL + l0) * RR);

    float h[16];
    #pragma unroll
    for (int i = 0; i < 16; ++i) h[i] = 0.f;
    float td = 0.f;

    __syncthreads();

    #pragma unroll 1
    for (int lb = 0; lb < CLEN / 12; ++lb) {
        float del[12];
        #pragma unroll
        for (int j = 0; j < 12; ++j) {
            int l = lb * 12 + j;
            float4 q0 = Dt[l*3+0], q1 = Dt[l*3+1], q2 = Dt[l*3+2];
            float acc = dtbv
                + q0.x*w12[0] + q0.y*w12[1] + q0.z*w12[2]  + q0.w*w12[3]
                + q1.x*w12[4] + q1.y*w12[5] + q1.z*w12[6]  + q1.w*w12[7]
                + q2.x*w12[8] + q2.y*w12[9] + q2.z*w12[10] + q2.w*w12[11];
            del[j] = softplus_f(acc);
        }
        #pragma unroll
        for (int j = 0; j < 12; ++j) {
            int l = lb * 12 + j;
            float delta = del[j];
            float u = *up; up += ustep;
            td += delta;
            float du = delta * u;
            const float4* Bl = (const float4*)&sB[l * 16];
            float4 B0 = Bl[0], B1 = Bl[1], B2 = Bl[2], B3 = Bl[3];
            h[0]  = h[0]  * fexp2(delta * A2[0])  + du * B0.x;
            h[1]  = h[1]  * fexp2(delta * A2[1])  + du * B0.y;
            h[2]  = h[2]  * fexp2(delta * A2[2])  + du * B0.z;
            h[3]  = h[3]  * fexp2(delta * A2[3])  + du * B0.w;
            h[4]  = h[4]  * fexp2(delta * A2[4])  + du * B1.x;
            h[5]  = h[5]  * fexp2(delta * A2[5])  + du * B1.y;
            h[6]  = h[6]  * fexp2(delta * A2[6])  + du * B1.z;
            h[7]  = h[7]  * fexp2(delta * A2[7])  + du * B1.w;
            h[8]  = h[8]  * fexp2(delta * A2[8])  + du * B2.x;
            h[9]  = h[9]  * fexp2(delta * A2[9])  + du * B2.y;
            h[10] = h[10] * fexp2(delta * A2[10]) + du * B2.z;
            h[11] = h[11] * fexp2(delta * A2[11]) + du * B2.w;
            h[12] = h[12] * fexp2(delta * A2[12]) + du * B3.x;
            h[13] = h[13] * fexp2(delta * A2[13]) + du * B3.y;
            h[14] = h[14] * fexp2(delta * A2[14]) + du * B3.z;
            h[15] = h[15] * fexp2(delta * A2[15]) + du * B3.w;
        }
    }

    float4* ho = (float4*)(hstin + ((size_t)(bk * CH + c) * DI + d) * NN);
    #pragma unroll
    for (int i = 0; i < 4; ++i) {
        float4 o; o.x = h[4*i]; o.y = h[4*i+1]; o.z = h[4*i+2]; o.w = h[4*i+3];
        ho[i] = o;
    }
    Tsum[(size_t)(bk * CH + c) * DI + d] = td;
}

// ---------------- combine (in-place): end-states -> incoming states
__global__ __launch_bounds__(256) void k_scan_combine(
    float* __restrict__ hstin,
    const float* __restrict__ Tsum,
    const float* __restrict__ Alogs)
{
    int t = blockIdx.x * 256 + threadIdx.x;   // B*K*DI*NN = 98304
    int n = t & 15;
    int d = (t >> 4) % DI;
    int bk = t / (DI * NN);
    int k = bk & 3;
    float A2 = -expf(Alogs[(size_t)(k * DI + d) * NN + n]) * LOG2E;
    float h = 0.f;
    for (int c = 0; c < CH; ++c) {
        size_t rb = (size_t)(bk * CH + c) * DI + d;
        float hend = hstin[rb * NN + n];
        hstin[rb * NN + n] = h;
        float St = Tsum[rb];
        h = fexp2(A2 * St) * h + hend;
    }
}

// ---------------- fat-lane pass2 (R14: CH=96, 192-thread d-half blocks).
__global__ __launch_bounds__(192) void k_scan_pass2(
    const float* __restrict__ xcT,
    const float* __restrict__ xcTt,
    const float* __restrict__ dts,
    const float* __restrict__ Bsb,
    const float* __restrict__ Csb,
    const float* __restrict__ dtw_g,
    const float* __restrict__ dtb_g,
    const float* __restrict__ Alogs,
    const float* __restrict__ Ds_g,
    const float* __restrict__ hin,
    float* __restrict__ yk)
{
    __shared__ float sB[CLEN * 16];      // 1.5 KB
    __shared__ float sC[CLEN * 16];      // 1.5 KB
    int blk = blockIdx.x;            // ((bk*CH + c)*2 + dh)
    int dh = blk & 1;
    int t2 = blk >> 1;
    int c = t2 % CH;
    int bk = t2 / CH;
    int k = bk & 3, b = bk >> 2;
    int tid = threadIdx.x;           // 0..191
    int d = dh * 192 + tid;
    int l0 = c * CLEN;
    int kd = k * DI + d;

    {   // coop stage: tid 0-95 -> B, 96-191 -> C (96 float4 each)
        const float4* Bg = (const float4*)(Bsb + ((size_t)bk * LL + l0) * NN);
        const float4* Cg = (const float4*)(Csb + ((size_t)bk * LL + l0) * NN);
        if (tid < 96) ((float4*)sB)[tid] = Bg[tid];
        else          ((float4*)sC)[tid - 96] = Cg[tid - 96];
    }

    float dtbv = dtb_g[kd];
    float w12[12];
    {
        const float4* p = (const float4*)(dtw_g + (size_t)kd * RR);
        float4 a0 = p[0], a1 = p[1], a2 = p[2];
        w12[0]=a0.x; w12[1]=a0.y; w12[2]=a0.z;  w12[3]=a0.w;
        w12[4]=a1.x; w12[5]=a1.y; w12[6]=a1.z;  w12[7]=a1.w;
        w12[8]=a2.x; w12[9]=a2.y; w12[10]=a2.z; w12[11]=a2.w;
    }
    float A2[16];
    {
        const float4* p = (const float4*)(Alogs + (size_t)kd * NN);
        #pragma unroll
        for (int i = 0; i < 4; ++i) {
            float4 a = p[i];
            A2[4*i+0] = -expf(a.x) * LOG2E;
            A2[4*i+1] = -expf(a.y) * LOG2E;
            A2[4*i+2] = -expf(a.z) * LOG2E;
            A2[4*i+3] = -expf(a.w) * LOG2E;
        }
    }
    float Dv = Ds_g[kd];

    const float* usrc = (k & 1) ? xcTt : xcT;
    int pbase = (k < 2) ? l0 : (LL - 1 - l0);
    int pstep = (k < 2) ? 1 : -1;
    const float* up = usrc + ((size_t)b * LL + pbase) * DI + d;
    ptrdiff_t ustep = (ptrdiff_t)pstep * DI;

    const float4* Dt = (const float4*)(dts + ((size_t)bk * LL + l0) * RR);

    float h[16];
    {
        const float4* hp = (const float4*)(hin + ((size_t)(bk * CH + c) * DI + d) * NN);
        #pragma unroll
        for (int i = 0; i < 4; ++i) {
            float4 a = hp[i];
            h[4*i] = a.x; h[4*i+1] = a.y; h[4*i+2] = a.z; h[4*i+3] = a.w;
        }
    }
    float* yc = yk + ((size_t)bk * LL + l0) * DI + d;

    __syncthreads();

    #pragma unroll 1
    for (int lb = 0; lb < CLEN / 12; ++lb) {
        float del[12];
        #pragma unroll
        for (int j = 0; j < 12; ++j) {
            int l = lb * 12 + j;
            float4 q0 = Dt[l*3+0], q1 = Dt[l*3+1], q2 = Dt[l*3+2];
            float acc = dtbv
                + q0.x*w12[0] + q0.y*w12[1] + q0.z*w12[2]  + q0.w*w12[3]
                + q1.x*w12[4] + q1.y*w12[5] + q1.z*w12[6]  + q1.w*w12[7]
                + q2.x*w12[8] + q2.y*w12[9] + q2.z*w12[10] + q2.w*w12[11];
            del[j] = softplus_f(acc);
        }
        #pragma unroll
        for (int j = 0; j < 12; ++j) {
            int l = lb * 12 + j;
            float delta = del[j];
            float u = *up; up += ustep;
            float du = delta * u;
            const float4* Bl = (const float4*)&sB[l * 16];
            float4 B0 = Bl[0], B1 = Bl[1], B2 = Bl[2], B3 = Bl[3];
            h[0]  = h[0]  * fexp2(delta * A2[0])  + du * B0.x;
            h[1]  = h[1]  * fexp2(delta * A2[1])  + du * B0.y;
            h[2]  = h[2]  * fexp2(delta * A2[2])  + du * B0.z;
            h[3]  = h[3]  * fexp2(delta * A2[3])  + du * B0.w;
            h[4]  = h[4]  * fexp2(delta * A2[4])  + du * B1.x;
            h[5]  = h[5]  * fexp2(delta * A2[5])  + du * B1.y;
            h[6]  = h[6]  * fexp2(delta * A2[6])  + du * B1.z;
            h[7]  = h[7]  * fexp2(delta * A2[7])  + du * B1.w;
            h[8]  = h[8]  * fexp2(delta * A2[8])  + du * B2.x;
            h[9]  = h[9]  * fexp2(delta * A2[9])  + du * B2.y;
            h[10] = h[10] * fexp2(delta * A2[10]) + du * B2.z;
            h[11] = h[11] * fexp2(delta * A2[11]) + du * B2.w;
            h[12] = h[12] * fexp2(delta * A2[12]) + du * B3.x;
            h[13] = h[13] * fexp2(delta * A2[13]) + du * B3.y;
            h[14] = h[14] * fexp2(delta * A2[14]) + du * B3.z;
            h[15] = h[15] * fexp2(delta * A2[15]) + du * B3.w;
            const float4* Cl = (const float4*)&sC[l * 16];
            float4 C0 = Cl[0], C1 = Cl[1], C2 = Cl[2], C3 = Cl[3];
            float y0 = h[0]*C0.x + h[1]*C0.y + h[2]*C0.z  + h[3]*C0.w;
            float y1 = h[4]*C1.x + h[5]*C1.y + h[6]*C1.z  + h[7]*C1.w;
            float y2 = h[8]*C2.x + h[9]*C2.y + h[10]*C2.z + h[11]*C2.w;
            float y3 = h[12]*C3.x + h[13]*C3.y + h[14]*C3.z + h[15]*C3.w;
            yc[(size_t)l * DI] = (y0 + y1) + (y2 + y3) + u * Dv;
        }
    }
}

// ---------------- merge (CrossMerge) + LayerNorm + gate -> bf16 gbuf
__global__ __launch_bounds__(384) void k_merge_ln_gate(
    const float* __restrict__ yk,
    const float* __restrict__ xcz,     // z at columns 384..767
    const float* __restrict__ lnw,
    const float* __restrict__ lnb,
    short* __restrict__ gbufb)
{
    int pg = blockIdx.x;            // b*LL + pos
    int b = pg / LL;
    int pos = pg % LL;
    int d = threadIdx.x;
    int pt = (pos % 48) * 48 + pos / 48;

    const float* y0 = yk + ((size_t)(b * 4 + 0) * LL + pos) * DI;
    const float* y1 = yk + ((size_t)(b * 4 + 1) * LL + pt) * DI;
    const float* y2 = yk + ((size_t)(b * 4 + 2) * LL + (LL - 1 - pos)) * DI;
    const float* y3 = yk + ((size_t)(b * 4 + 3) * LL + (LL - 1 - pt)) * DI;
    float v = y0[d] + y1[d] + y2[d] + y3[d];

    float s = v, qq = v * v;
    #pragma unroll
    for (int o = 32; o >= 1; o >>= 1) {
        s += __shfl_xor(s, o, 64);
        qq += __shfl_xor(qq, o, 64);
    }
    __shared__ float ssum[6], sqq[6];
    int lane = d & 63, w = d >> 6;
    if (lane == 0) { ssum[w] = s; sqq[w] = qq; }
    __syncthreads();
    float ts = 0.f, tq = 0.f;
    #pragma unroll
    for (int i = 0; i < 6; ++i) { ts += ssum[i]; tq += sqq[i]; }
    float mu = ts / (float)DI;
    float var = tq / (float)DI - mu * mu;
    float inv = rsqrtf(var + 1e-5f);
    float y = (v - mu) * inv * lnw[d] + lnb[d];
    float z = xcz[(size_t)pg * 768 + DI + d];
    gbufb[(size_t)pg * DI + d] = f2bf(y * z);
}

// ---------------- K6: out_proj via bf16 MFMA. K=384, tile 128l x 64o.
__global__ __launch_bounds__(256) void k_outproj_mfma(
    const short* __restrict__ gbufb,   // (B,L,384) bf16
    const short* __restrict__ owbf,    // (192,384) bf16
    float* __restrict__ out)           // (B,192,L) fp32
{
    __shared__ short sA[128 * 40];
    __shared__ short sB[64 * 40];
    int o0 = blockIdx.x * 64;
    int l0 = blockIdx.y * 128;
    int b  = blockIdx.z;
    int tid = threadIdx.x;
    int lane = tid & 63, wid = tid >> 6;
    int n = lane & 15, quad = lane >> 4;

    v4f acc[2][4];
    #pragma unroll
    for (int i = 0; i < 2; ++i)
        #pragma unroll
        for (int j = 0; j < 4; ++j) acc[i][j] = (v4f){0.f, 0.f, 0.f, 0.f};

    for (int kc = 0; kc < DI; kc += 32) {
        for (int i = tid; i < 512; i += 256) {
            int row = i >> 2, seg = i & 3;
            *(v8s*)&sA[row * 40 + seg * 8] =
                *(const v8s*)(gbufb + (size_t)(b * LL + l0 + row) * DI + kc + seg * 8);
        }
        {
            int row = tid >> 2, seg = tid & 3;
            *(v8s*)&sB[row * 40 + seg * 8] =
                *(const v8s*)(owbf + (size_t)(o0 + row) * DI + kc + seg * 8);
        }
        __syncthreads();
        v8s a0 = *(v8s*)&sA[(wid * 32 + n) * 40 + quad * 8];
        v8s a1 = *(v8s*)&sA[(wid * 32 + 16 + n) * 40 + quad * 8];
        #pragma unroll
        for (int os = 0; os < 4; ++os) {
            v8s bv = *(v8s*)&sB[(os * 16 + n) * 40 + quad * 8];
            acc[0][os] = __builtin_amdgcn_mfma_f32_16x16x32_bf16(a0, bv, acc[0][os], 0, 0, 0);
            acc[1][os] = __builtin_amdgcn_mfma_f32_16x16x32_bf16(a1, bv, acc[1][os], 0, 0, 0);
        }
        __syncthreads();
    }
    #pragma unroll
    for (int ls = 0; ls < 2; ++ls)
        #pragma unroll
        for (int os = 0; os < 4; ++os) {
            int o = o0 + os * 16 + n;
            #pragma unroll
            for (int r = 0; r < 4; ++r) {
                int l = l0 + wid * 32 + ls * 16 + quad * 4 + r;
                out[(size_t)(b * DM + o) * LL + l] = acc[ls][os][r];
            }
        }
}

extern "C" void kernel_launch(void* const* d_in, const int* in_sizes, int n_in,
                              void* d_out, int out_size, void* d_ws, size_t ws_size,
                              hipStream_t stream) {
    (void)in_sizes; (void)n_in; (void)out_size; (void)ws_size;
    const float* x      = (const float*)d_in[0];
    const float* ipw    = (const float*)d_in[1];
    const float* cw     = (const float*)d_in[2];
    const float* cb     = (const float*)d_in[3];
    const float* xpw    = (const float*)d_in[4];
    const float* dtw    = (const float*)d_in[5];
    const float* dtb    = (const float*)d_in[6];
    const float* Alogs  = (const float*)d_in[7];
    const float* Ds     = (const float*)d_in[8];
    const float* lnw    = (const float*)d_in[9];
    const float* lnb    = (const float*)d_in[10];
    const float* opw    = (const float*)d_in[11];
    float* out = (float*)d_out;

    float* wsf = (float*)d_ws;
    const size_t XCZ = (size_t)BQ * LL * 768;             //  7,077,888
    const size_t SZ  = (size_t)BQ * DI * LL;              //  3,538,944
    const size_t DTS = (size_t)BQ * KK * LL * RR;         //    442,368
    const size_t BCS = (size_t)BQ * KK * LL * NN;         //    589,824
    const size_t TSM = (size_t)BQ * KK * CH * DI;         //    589,824
    const size_t SBF = (size_t)BQ * KK * LL * DI;         // 14,155,776
    const size_t HST = (size_t)BQ * KK * CH * DI * NN;    //  9,437,184

    float* xcz   = wsf;                  // (B,L,768): xc half + gelu(z) half
    float* xcT   = xcz + XCZ;            // (B,L,384) fp32 conv output (scan u)
    float* xcTt  = xcT + SZ;             // (B,L,384) fp32, transposed row order
    float* dts   = xcTt + SZ;            // (B,K,L,R)
    float* Bsb   = dts + DTS;            // (B,K,L,N)
    float* Csb   = Bsb + BCS;            // (B,K,L,N)
    float* Tsum  = Csb + BCS;            // (B,K,CH,DI) chunk delta totals
    float* hstin = Tsum + TSM;           // (B,K,CH,DI,N)
    float* yk    = hstin + HST;          // (B,K,L,DI)
    short* xTbf  = (short*)(yk + SBF);   // (B,L,192) bf16 in_proj input
    short* wibf  = xTbf + (size_t)BQ * LL * DM;   // (768,192)
    short* owbf  = wibf + 768 * 192;              // (192,384)
    short* wpbf  = owbf + 192 * 384;              // (192,384) x_proj padded
    short* gbufb = wpbf + 192 * 384;              // (B,L,384) bf16 gate output
    // xcTbf (B*L*384 shorts) aliases yk: xcTbf dead after k_xproj_mfma; yk
    // first written by k_scan_pass2 (after).
    short* xcTbf = (short*)yk;

    k_prep_w<<<1152, 256, 0, stream>>>(ipw, opw, xpw, wibf, owbf, wpbf);
    k_prep_xT<<<BQ * 72 * 6, 256, 0, stream>>>(x, xTbf);
    k_inproj_mfma<<<dim3(12, 18, BQ), 256, 0, stream>>>(xTbf, wibf, xcz);
    k_dwconv<<<BQ * HH * 4, 384, 0, stream>>>(xcz, cw, cb, xcT, xcTt, xcTbf);
    k_xproj_mfma<<<dim3(3, 18, BQ), 256, 0, stream>>>(xcTbf, wpbf, dts, Bsb, Csb);

    k_scan_pass1<<<BQ * KK * CH * 2, 192, 0, stream>>>(
        xcT, xcTt, dts, Bsb, dtw, dtb, Alogs, hstin, Tsum);
    k_scan_combine<<<(BQ * KK * DI * NN) / 256, 256, 0, stream>>>(
        hstin, Tsum, Alogs);
    k_scan_pass2<<<BQ * KK * CH * 2, 192, 0, stream>>>(
        xcT, xcTt, dts, Bsb, Csb, dtw, dtb, Alogs, Ds, hstin, yk);
    k_merge_ln_gate<<<BQ * LL, 384, 0, stream>>>(yk, xcz, lnw, lnb, gbufb);

    k_outproj_mfma<<<dim3(3, 18, BQ), 256, 0, stream>>>(gbufb, owbf, out);
}

// Round 15
// 265.903 us; speedup vs baseline: 1.0673x; 1.0533x over previous
//
#include <hip/hip_runtime.h>
#include <math.h>

#define BQ 4
#define DM 192
#define DI 384
#define HH 48
#define WW 48
#define LL 2304
#define KK 4
#define NN 16
#define RR 12
#define CH 96      // chunks per sequence
#define CLEN 24    // chunk length

#define LOG2E 1.4426950408889634f
#define LN2   0.6931471805599453f

typedef short v8s __attribute__((ext_vector_type(8)));
typedef float v4f __attribute__((ext_vector_type(4)));
typedef float v2f __attribute__((ext_vector_type(2)));

__device__ __forceinline__ float gelu_exact(float x) {
    return 0.5f * x * (1.0f + erff(x * 0.7071067811865476f));
}

__device__ __forceinline__ float fexp2(float x) {
    return __builtin_amdgcn_exp2f(x);
}

__device__ __forceinline__ float flog2(float x) {
    return __builtin_amdgcn_logf(x);
}

// softplus via hw exp2/log2: max(x,0) + ln2*log2(1 + 2^(-|x|*log2e))
__device__ __forceinline__ float softplus_f(float x) {
    float t = fexp2(-fabsf(x) * LOG2E);
    return fmaxf(x, 0.0f) + LN2 * flog2(1.0f + t);
}

__device__ __forceinline__ int pt_of(int p) {   // 48x48 transpose, involution
    return (p % 48) * 48 + p / 48;
}

__device__ __forceinline__ short f2bf(float x) {
    unsigned u = __float_as_uint(x);
    unsigned r = (u + 0x7FFFu + ((u >> 16) & 1u)) >> 16;
    return (short)r;
}

// ---------------- P1: cast weights to bf16. wpbf = x_proj (176,384) padded to 192 rows.
__global__ __launch_bounds__(256) void k_prep_w(const float* __restrict__ ipw,
                                                const float* __restrict__ opw,
                                                const float* __restrict__ xpw,
                                                short* __restrict__ wibf,
                                                short* __restrict__ owbf,
                                                short* __restrict__ wpbf) {
    int i = blockIdx.x * 256 + threadIdx.x;     // 1152*256 = 294912 exactly
    if (i < 147456)       wibf[i] = f2bf(ipw[i]);
    else if (i < 221184)  owbf[i - 147456] = f2bf(opw[i - 147456]);
    else if (i < 288768)  wpbf[i - 221184] = f2bf(xpw[i - 221184]);
    else                  wpbf[67584 + (i - 288768)] = 0;   // pad rows 176..191
}

// ---------------- P2: transpose-cast x (B,192,L) -> xTbf (B,L,192) bf16
__global__ __launch_bounds__(256) void k_prep_xT(const float* __restrict__ x,
                                                 short* __restrict__ xTbf) {
    __shared__ float T[32][33];
    int blk = blockIdx.x;           // (b*72 + lt)*6 + dt
    int dt = blk % 6;
    int lt = (blk / 6) % 72;
    int b  = blk / (6 * 72);
    int d0 = dt * 32, l0 = lt * 32;
    int tx = threadIdx.x & 31, ty = threadIdx.x >> 5;   // ty 0..7
    #pragma unroll
    for (int i = 0; i < 4; ++i) {
        int dd = ty + 8 * i;
        T[dd][tx] = x[(size_t)(b * DM + d0 + dd) * LL + l0 + tx];
    }
    __syncthreads();
    #pragma unroll
    for (int i = 0; i < 4; ++i) {
        int ll = ty + 8 * i;
        xTbf[(size_t)(b * LL + l0 + ll) * DM + d0 + tx] = f2bf(T[tx][ll]);
    }
}

// ---------------- K1: in_proj via bf16 MFMA. D[l][o]; o<384 -> xc, else gelu->z.
__global__ __launch_bounds__(256) void k_inproj_mfma(
    const short* __restrict__ xTbf,   // (B,L,192) bf16
    const short* __restrict__ wibf,   // (768,192) bf16
    float* __restrict__ xcz)          // (B,L,768) fp32
{
    __shared__ short sA[128 * 40];    // [l][k32], row stride 40 shorts
    __shared__ short sB[64 * 40];     // [o][k32]
    int o0 = blockIdx.x * 64;
    int l0 = blockIdx.y * 128;
    int b  = blockIdx.z;
    int tid = threadIdx.x;
    int lane = tid & 63, wid = tid >> 6;
    int n = lane & 15, quad = lane >> 4;

    v4f acc[2][4];
    #pragma unroll
    for (int i = 0; i < 2; ++i)
        #pragma unroll
        for (int j = 0; j < 4; ++j) acc[i][j] = (v4f){0.f, 0.f, 0.f, 0.f};

    for (int kc = 0; kc < 192; kc += 32) {
        for (int i = tid; i < 512; i += 256) {
            int row = i >> 2, seg = i & 3;
            *(v8s*)&sA[row * 40 + seg * 8] =
                *(const v8s*)(xTbf + (size_t)(b * LL + l0 + row) * DM + kc + seg * 8);
        }
        {
            int row = tid >> 2, seg = tid & 3;
            *(v8s*)&sB[row * 40 + seg * 8] =
                *(const v8s*)(wibf + (size_t)(o0 + row) * DM + kc + seg * 8);
        }
        __syncthreads();
        v8s a0 = *(v8s*)&sA[(wid * 32 + n) * 40 + quad * 8];
        v8s a1 = *(v8s*)&sA[(wid * 32 + 16 + n) * 40 + quad * 8];
        #pragma unroll
        for (int os = 0; os < 4; ++os) {
            v8s bv = *(v8s*)&sB[(os * 16 + n) * 40 + quad * 8];
            acc[0][os] = __builtin_amdgcn_mfma_f32_16x16x32_bf16(a0, bv, acc[0][os], 0, 0, 0);
            acc[1][os] = __builtin_amdgcn_mfma_f32_16x16x32_bf16(a1, bv, acc[1][os], 0, 0, 0);
        }
        __syncthreads();
    }
    bool zhalf = (o0 >= DI);
    #pragma unroll
    for (int ls = 0; ls < 2; ++ls)
        #pragma unroll
        for (int os = 0; os < 4; ++os) {
            int o = o0 + os * 16 + n;
            #pragma unroll
            for (int r = 0; r < 4; ++r) {
                int l = l0 + wid * 32 + ls * 16 + quad * 4 + r;
                float v = acc[ls][os][r];
                xcz[(size_t)(b * LL + l) * 768 + o] = zhalf ? gelu_exact(v) : v;
            }
        }
}

// ---------------- K2: depthwise 3x3 conv + bias + gelu, [l][c] layout.
// Writes xcT fp32 (row-major), xcTt fp32 (transposed row order) and xcTbf bf16.
__global__ __launch_bounds__(384) void k_dwconv(const float* __restrict__ xcz,
                                                const float* __restrict__ cw,
                                                const float* __restrict__ cb,
                                                float* __restrict__ xcT,
                                                float* __restrict__ xcTt,
                                                short* __restrict__ xcTbf) {
    int blk = blockIdx.x;           // ((b*HH + h)*4 + seg)
    int seg = blk & 3;
    int bh = blk >> 2;
    int b = bh / HH, h = bh % HH;
    int d = threadIdx.x;
    int w0 = seg * 12;
    const float* in = xcz + (size_t)b * LL * 768 + d;
    float w9[9];
    #pragma unroll
    for (int i = 0; i < 9; ++i) w9[i] = cw[d * 9 + i];
    float bias = cb[d];
    bool hm = h > 0, hp = h < HH - 1;
    int r0 = (h - 1) * WW, r1 = h * WW, r2 = (h + 1) * WW;
    float c00, c01, c02, c10, c11, c12, c20, c21, c22;
    bool wl = (w0 > 0);
    c00 = (hm && wl) ? in[(size_t)(r0 + w0 - 1) * 768] : 0.f;
    c10 = wl ? in[(size_t)(r1 + w0 - 1) * 768] : 0.f;
    c20 = (hp && wl) ? in[(size_t)(r2 + w0 - 1) * 768] : 0.f;
    c01 = hm ? in[(size_t)(r0 + w0) * 768] : 0.f;
    c11 = in[(size_t)(r1 + w0) * 768];
    c21 = hp ? in[(size_t)(r2 + w0) * 768] : 0.f;
    c02 = hm ? in[(size_t)(r0 + w0 + 1) * 768] : 0.f;
    c12 = in[(size_t)(r1 + w0 + 1) * 768];
    c22 = hp ? in[(size_t)(r2 + w0 + 1) * 768] : 0.f;
    #pragma unroll
    for (int wi = 0; wi < 12; ++wi) {
        int w = w0 + wi;
        float s = bias
            + w9[0] * c00 + w9[1] * c01 + w9[2] * c02
            + w9[3] * c10 + w9[4] * c11 + w9[5] * c12
            + w9[6] * c20 + w9[7] * c21 + w9[8] * c22;
        float v = gelu_exact(s);
        int pos = h * WW + w;
        size_t row  = (size_t)b * LL + pos;
        size_t rowt = (size_t)b * LL + (w * 48 + h);   // pt(pos)
        xcT[row * DI + d] = v;
        xcTt[rowt * DI + d] = v;
        xcTbf[row * DI + d] = f2bf(v);
        c00 = c01; c01 = c02; c10 = c11; c11 = c12; c20 = c21; c21 = c22;
        int wn = w + 2;
        bool okw = wn < WW;
        c02 = (hm && okw) ? in[(size_t)(r0 + wn) * 768] : 0.f;
        c12 = okw ? in[(size_t)(r1 + wn) * 768] : 0.f;
        c22 = (hp && okw) ? in[(size_t)(r2 + wn) * 768] : 0.f;
    }
}

// ---------------- K3: x_proj, ALL 4 directions as ONE bf16 MFMA GEMM.
__global__ __launch_bounds__(256) void k_xproj_mfma(
    const short* __restrict__ xcTbf,  // (B,L,384) bf16
    const short* __restrict__ wpbf,   // (192,384) bf16, rows>=176 zero
    float* __restrict__ dts,
    float* __restrict__ Bsb,
    float* __restrict__ Csb)
{
    __shared__ short sA[128 * 40];
    __shared__ short sB[64 * 40];
    int o0 = blockIdx.x * 64;
    int l0 = blockIdx.y * 128;
    int b  = blockIdx.z;
    int tid = threadIdx.x;
    int lane = tid & 63, wid = tid >> 6;
    int n = lane & 15, quad = lane >> 4;

    v4f acc[2][4];
    #pragma unroll
    for (int i = 0; i < 2; ++i)
        #pragma unroll
        for (int j = 0; j < 4; ++j) acc[i][j] = (v4f){0.f, 0.f, 0.f, 0.f};

    for (int kc = 0; kc < DI; kc += 32) {
        for (int i = tid; i < 512; i += 256) {
            int row = i >> 2, seg = i & 3;
            *(v8s*)&sA[row * 40 + seg * 8] =
                *(const v8s*)(xcTbf + (size_t)(b * LL + l0 + row) * DI + kc + seg * 8);
        }
        {
            int row = tid >> 2, seg = tid & 3;
            *(v8s*)&sB[row * 40 + seg * 8] =
                *(const v8s*)(wpbf + (size_t)(o0 + row) * DI + kc + seg * 8);
        }
        __syncthreads();
        v8s a0 = *(v8s*)&sA[(wid * 32 + n) * 40 + quad * 8];
        v8s a1 = *(v8s*)&sA[(wid * 32 + 16 + n) * 40 + quad * 8];
        #pragma unroll
        for (int os = 0; os < 4; ++os) {
            v8s bv = *(v8s*)&sB[(os * 16 + n) * 40 + quad * 8];
            acc[0][os] = __builtin_amdgcn_mfma_f32_16x16x32_bf16(a0, bv, acc[0][os], 0, 0, 0);
            acc[1][os] = __builtin_amdgcn_mfma_f32_16x16x32_bf16(a1, bv, acc[1][os], 0, 0, 0);
        }
        __syncthreads();
    }
    #pragma unroll
    for (int ls = 0; ls < 2; ++ls)
        #pragma unroll
        for (int os = 0; os < 4; ++os) {
            int c_all = o0 + os * 16 + n;
            if (c_all >= 176) continue;
            int k = c_all / 44;
            int c = c_all - k * 44;
            int bk = b * 4 + k;
            #pragma unroll
            for (int r = 0; r < 4; ++r) {
                int lp = l0 + wid * 32 + ls * 16 + quad * 4 + r;
                int lk = (k == 0) ? lp
                       : (k == 1) ? pt_of(lp)
                       : (k == 2) ? (LL - 1 - lp)
                                  : (LL - 1 - pt_of(lp));
                float v = acc[ls][os][r];
                size_t base = (size_t)bk * LL + lk;
                if (c < RR)           dts[base * RR + c] = v;
                else if (c < RR + NN) Bsb[base * NN + (c - RR)] = v;
                else                  Csb[base * NN + (c - RR - NN)] = v;
            }
        }
}

// ---------------- fat-lane pass1 (R14 structure + PACKED fp32 math).
// pass2 measured 183 cyc/wave-iter == ~90 VALU instr x 2cyc: VALU-issue-bound.
// float2 ext-vectors lower mul/fma to v_pk_mul_f32/v_pk_fma_f32 (2 states per
// instruction); only the 16 v_exp_f32 stay scalar (separate trans pipe).
__global__ __launch_bounds__(192) void k_scan_pass1(
    const float* __restrict__ xcT,
    const float* __restrict__ xcTt,
    const float* __restrict__ dts,
    const float* __restrict__ Bsb,
    const float* __restrict__ dtw_g,
    const float* __restrict__ dtb_g,
    const float* __restrict__ Alogs,
    float* __restrict__ hstin,
    float* __restrict__ Tsum)
{
    __shared__ float sB[CLEN * 16];      // 1.5 KB, [l][n]
    int blk = blockIdx.x;            // ((bk*CH + c)*2 + dh)
    int dh = blk & 1;
    int t2 = blk >> 1;
    int c = t2 % CH;
    int bk = t2 / CH;
    int k = bk & 3, b = bk >> 2;
    int tid = threadIdx.x;           // 0..191
    int d = dh * 192 + tid;
    int l0 = c * CLEN;
    int kd = k * DI + d;

    {   // coop stage: CLEN*16 floats = 96 float4
        const float4* Bg = (const float4*)(Bsb + ((size_t)bk * LL + l0) * NN);
        if (tid < 96) ((float4*)sB)[tid] = Bg[tid];
    }

    float dtbv = dtb_g[kd];
    v2f w2[6];
    {
        const v2f* p = (const v2f*)(dtw_g + (size_t)kd * RR);
        #pragma unroll
        for (int i = 0; i < 6; ++i) w2[i] = p[i];
    }
    v2f A22[8];
    {
        const float4* p = (const float4*)(Alogs + (size_t)kd * NN);
        #pragma unroll
        for (int i = 0; i < 4; ++i) {
            float4 a = p[i];
            A22[2*i]   = (v2f){-expf(a.x) * LOG2E, -expf(a.y) * LOG2E};
            A22[2*i+1] = (v2f){-expf(a.z) * LOG2E, -expf(a.w) * LOG2E};
        }
    }

    const float* usrc = (k & 1) ? xcTt : xcT;
    int pbase = (k < 2) ? l0 : (LL - 1 - l0);
    int pstep = (k < 2) ? 1 : -1;
    const float* up = usrc + ((size_t)b * LL + pbase) * DI + d;
    ptrdiff_t ustep = (ptrdiff_t)pstep * DI;

    const v2f* Drow = (const v2f*)(dts + ((size_t)bk * LL + l0) * RR);

    v2f h2[8];
    #pragma unroll
    for (int i = 0; i < 8; ++i) h2[i] = (v2f){0.f, 0.f};
    float td = 0.f;

    __syncthreads();

    #pragma unroll 1
    for (int lb = 0; lb < CLEN / 12; ++lb) {
        float del[12];
        #pragma unroll
        for (int j = 0; j < 12; ++j) {
            int l = lb * 12 + j;
            v2f acc2 = Drow[l*6+0] * w2[0];
            acc2 += Drow[l*6+1] * w2[1];
            acc2 += Drow[l*6+2] * w2[2];
            acc2 += Drow[l*6+3] * w2[3];
            acc2 += Drow[l*6+4] * w2[4];
            acc2 += Drow[l*6+5] * w2[5];
            del[j] = softplus_f(dtbv + acc2.x + acc2.y);
        }
        #pragma unroll
        for (int j = 0; j < 12; ++j) {
            int l = lb * 12 + j;
            float delta = del[j];
            float u = *up; up += ustep;
            td += delta;
            float du = delta * u;
            v2f du2 = (v2f){du, du};
            v2f dl2 = (v2f){delta, delta};
            const v2f* Bl = (const v2f*)&sB[l * 16];
            #pragma unroll
            for (int i = 0; i < 8; ++i) {
                v2f t = dl2 * A22[i];
                v2f e; e.x = fexp2(t.x); e.y = fexp2(t.y);
                h2[i] = h2[i] * e + du2 * Bl[i];
            }
        }
    }

    float4* ho = (float4*)(hstin + ((size_t)(bk * CH + c) * DI + d) * NN);
    #pragma unroll
    for (int i = 0; i < 4; ++i) {
        float4 o;
        o.x = h2[2*i].x; o.y = h2[2*i].y; o.z = h2[2*i+1].x; o.w = h2[2*i+1].y;
        ho[i] = o;
    }
    Tsum[(size_t)(bk * CH + c) * DI + d] = td;
}

// ---------------- combine (in-place): end-states -> incoming states
__global__ __launch_bounds__(256) void k_scan_combine(
    float* __restrict__ hstin,
    const float* __restrict__ Tsum,
    const float* __restrict__ Alogs)
{
    int t = blockIdx.x * 256 + threadIdx.x;   // B*K*DI*NN = 98304
    int n = t & 15;
    int d = (t >> 4) % DI;
    int bk = t / (DI * NN);
    int k = bk & 3;
    float A2 = -expf(Alogs[(size_t)(k * DI + d) * NN + n]) * LOG2E;
    float h = 0.f;
    for (int c = 0; c < CH; ++c) {
        size_t rb = (size_t)(bk * CH + c) * DI + d;
        float hend = hstin[rb * NN + n];
        hstin[rb * NN + n] = h;
        float St = Tsum[rb];
        h = fexp2(A2 * St) * h + hend;
    }
}

// ---------------- fat-lane pass2 (R14 structure + PACKED fp32 math).
__global__ __launch_bounds__(192) void k_scan_pass2(
    const float* __restrict__ xcT,
    const float* __restrict__ xcTt,
    const float* __restrict__ dts,
    const float* __restrict__ Bsb,
    const float* __restrict__ Csb,
    const float* __restrict__ dtw_g,
    const float* __restrict__ dtb_g,
    const float* __restrict__ Alogs,
    const float* __restrict__ Ds_g,
    const float* __restrict__ hin,
    float* __restrict__ yk)
{
    __shared__ float sB[CLEN * 16];      // 1.5 KB
    __shared__ float sC[CLEN * 16];      // 1.5 KB
    int blk = blockIdx.x;            // ((bk*CH + c)*2 + dh)
    int dh = blk & 1;
    int t2 = blk >> 1;
    int c = t2 % CH;
    int bk = t2 / CH;
    int k = bk & 3, b = bk >> 2;
    int tid = threadIdx.x;           // 0..191
    int d = dh * 192 + tid;
    int l0 = c * CLEN;
    int kd = k * DI + d;

    {   // coop stage: tid 0-95 -> B, 96-191 -> C (96 float4 each)
        const float4* Bg = (const float4*)(Bsb + ((size_t)bk * LL + l0) * NN);
        const float4* Cg = (const float4*)(Csb + ((size_t)bk * LL + l0) * NN);
        if (tid < 96) ((float4*)sB)[tid] = Bg[tid];
        else          ((float4*)sC)[tid - 96] = Cg[tid - 96];
    }

    float dtbv = dtb_g[kd];
    v2f w2[6];
    {
        const v2f* p = (const v2f*)(dtw_g + (size_t)kd * RR);
        #pragma unroll
        for (int i = 0; i < 6; ++i) w2[i] = p[i];
    }
    v2f A22[8];
    {
        const float4* p = (const float4*)(Alogs + (size_t)kd * NN);
        #pragma unroll
        for (int i = 0; i < 4; ++i) {
            float4 a = p[i];
            A22[2*i]   = (v2f){-expf(a.x) * LOG2E, -expf(a.y) * LOG2E};
            A22[2*i+1] = (v2f){-expf(a.z) * LOG2E, -expf(a.w) * LOG2E};
        }
    }
    float Dv = Ds_g[kd];

    const float* usrc = (k & 1) ? xcTt : xcT;
    int pbase = (k < 2) ? l0 : (LL - 1 - l0);
    int pstep = (k < 2) ? 1 : -1;
    const float* up = usrc + ((size_t)b * LL + pbase) * DI + d;
    ptrdiff_t ustep = (ptrdiff_t)pstep * DI;

    const v2f* Drow = (const v2f*)(dts + ((size_t)bk * LL + l0) * RR);

    v2f h2[8];
    {
        const float4* hp = (const float4*)(hin + ((size_t)(bk * CH + c) * DI + d) * NN);
        #pragma unroll
        for (int i = 0; i < 4; ++i) {
            float4 a = hp[i];
            h2[2*i]   = (v2f){a.x, a.y};
            h2[2*i+1] = (v2f){a.z, a.w};
        }
    }
    float* yc = yk + ((size_t)bk * LL + l0) * DI + d;

    __syncthreads();

    #pragma unroll 1
    for (int lb = 0; lb < CLEN / 12; ++lb) {
        float del[12];
        #pragma unroll
        for (int j = 0; j < 12; ++j) {
            int l = lb * 12 + j;
            v2f acc2 = Drow[l*6+0] * w2[0];
            acc2 += Drow[l*6+1] * w2[1];
            acc2 += Drow[l*6+2] * w2[2];
            acc2 += Drow[l*6+3] * w2[3];
            acc2 += Drow[l*6+4] * w2[4];
            acc2 += Drow[l*6+5] * w2[5];
            del[j] = softplus_f(dtbv + acc2.x + acc2.y);
        }
        #pragma unroll
        for (int j = 0; j < 12; ++j) {
            int l = lb * 12 + j;
            float delta = del[j];
            float u = *up; up += ustep;
            float du = delta * u;
            v2f du2 = (v2f){du, du};
            v2f dl2 = (v2f){delta, delta};
            const v2f* Bl = (const v2f*)&sB[l * 16];
            const v2f* Cl = (const v2f*)&sC[l * 16];
            v2f yacc = (v2f){0.f, 0.f};
            #pragma unroll
            for (int i = 0; i < 8; ++i) {
                v2f t = dl2 * A22[i];
                v2f e; e.x = fexp2(t.x); e.y = fexp2(t.y);
                h2[i] = h2[i] * e + du2 * Bl[i];
                yacc += h2[i] * Cl[i];
            }
            yc[(size_t)l * DI] = yacc.x + yacc.y + u * Dv;
        }
    }
}

// ---------------- merge (CrossMerge) + LayerNorm + gate -> bf16 gbuf
__global__ __launch_bounds__(384) void k_merge_ln_gate(
    const float* __restrict__ yk,
    const float* __restrict__ xcz,     // z at columns 384..767
    const float* __restrict__ lnw,
    const float* __restrict__ lnb,
    short* __restrict__ gbufb)
{
    int pg = blockIdx.x;            // b*LL + pos
    int b = pg / LL;
    int pos = pg % LL;
    int d = threadIdx.x;
    int pt = (pos % 48) * 48 + pos / 48;

    const float* y0 = yk + ((size_t)(b * 4 + 0) * LL + pos) * DI;
    const float* y1 = yk + ((size_t)(b * 4 + 1) * LL + pt) * DI;
    const float* y2 = yk + ((size_t)(b * 4 + 2) * LL + (LL - 1 - pos)) * DI;
    const float* y3 = yk + ((size_t)(b * 4 + 3) * LL + (LL - 1 - pt)) * DI;
    float v = y0[d] + y1[d] + y2[d] + y3[d];

    float s = v, qq = v * v;
    #pragma unroll
    for (int o = 32; o >= 1; o >>= 1) {
        s += __shfl_xor(s, o, 64);
        qq += __shfl_xor(qq, o, 64);
    }
    __shared__ float ssum[6], sqq[6];
    int lane = d & 63, w = d >> 6;
    if (lane == 0) { ssum[w] = s; sqq[w] = qq; }
    __syncthreads();
    float ts = 0.f, tq = 0.f;
    #pragma unroll
    for (int i = 0; i < 6; ++i) { ts += ssum[i]; tq += sqq[i]; }
    float mu = ts / (float)DI;
    float var = tq / (float)DI - mu * mu;
    float inv = rsqrtf(var + 1e-5f);
    float y = (v - mu) * inv * lnw[d] + lnb[d];
    float z = xcz[(size_t)pg * 768 + DI + d];
    gbufb[(size_t)pg * DI + d] = f2bf(y * z);
}

// ---------------- K6: out_proj via bf16 MFMA. K=384, tile 128l x 64o.
__global__ __launch_bounds__(256) void k_outproj_mfma(
    const short* __restrict__ gbufb,   // (B,L,384) bf16
    const short* __restrict__ owbf,    // (192,384) bf16
    float* __restrict__ out)           // (B,192,L) fp32
{
    __shared__ short sA[128 * 40];
    __shared__ short sB[64 * 40];
    int o0 = blockIdx.x * 64;
    int l0 = blockIdx.y * 128;
    int b  = blockIdx.z;
    int tid = threadIdx.x;
    int lane = tid & 63, wid = tid >> 6;
    int n = lane & 15, quad = lane >> 4;

    v4f acc[2][4];
    #pragma unroll
    for (int i = 0; i < 2; ++i)
        #pragma unroll
        for (int j = 0; j < 4; ++j) acc[i][j] = (v4f){0.f, 0.f, 0.f, 0.f};

    for (int kc = 0; kc < DI; kc += 32) {
        for (int i = tid; i < 512; i += 256) {
            int row = i >> 2, seg = i & 3;
            *(v8s*)&sA[row * 40 + seg * 8] =
                *(const v8s*)(gbufb + (size_t)(b * LL + l0 + row) * DI + kc + seg * 8);
        }
        {
            int row = tid >> 2, seg = tid & 3;
            *(v8s*)&sB[row * 40 + seg * 8] =
                *(const v8s*)(owbf + (size_t)(o0 + row) * DI + kc + seg * 8);
        }
        __syncthreads();
        v8s a0 = *(v8s*)&sA[(wid * 32 + n) * 40 + quad * 8];
        v8s a1 = *(v8s*)&sA[(wid * 32 + 16 + n) * 40 + quad * 8];
        #pragma unroll
        for (int os = 0; os < 4; ++os) {
            v8s bv = *(v8s*)&sB[(os * 16 + n) * 40 + quad * 8];
            acc[0][os] = __builtin_amdgcn_mfma_f32_16x16x32_bf16(a0, bv, acc[0][os], 0, 0, 0);
            acc[1][os] = __builtin_amdgcn_mfma_f32_16x16x32_bf16(a1, bv, acc[1][os], 0, 0, 0);
        }
        __syncthreads();
    }
    #pragma unroll
    for (int ls = 0; ls < 2; ++ls)
        #pragma unroll
        for (int os = 0; os < 4; ++os) {
            int o = o0 + os * 16 + n;
            #pragma unroll
            for (int r = 0; r < 4; ++r) {
                int l = l0 + wid * 32 + ls * 16 + quad * 4 + r;
                out[(size_t)(b * DM + o) * LL + l] = acc[ls][os][r];
            }
        }
}

extern "C" void kernel_launch(void* const* d_in, const int* in_sizes, int n_in,
                              void* d_out, int out_size, void* d_ws, size_t ws_size,
                              hipStream_t stream) {
    (void)in_sizes; (void)n_in; (void)out_size; (void)ws_size;
    const float* x      = (const float*)d_in[0];
    const float* ipw    = (const float*)d_in[1];
    const float* cw     = (const float*)d_in[2];
    const float* cb     = (const float*)d_in[3];
    const float* xpw    = (const float*)d_in[4];
    const float* dtw    = (const float*)d_in[5];
    const float* dtb    = (const float*)d_in[6];
    const float* Alogs  = (const float*)d_in[7];
    const float* Ds     = (const float*)d_in[8];
    const float* lnw    = (const float*)d_in[9];
    const float* lnb    = (const float*)d_in[10];
    const float* opw    = (const float*)d_in[11];
    float* out = (float*)d_out;

    float* wsf = (float*)d_ws;
    const size_t XCZ = (size_t)BQ * LL * 768;             //  7,077,888
    const size_t SZ  = (size_t)BQ * DI * LL;              //  3,538,944
    const size_t DTS = (size_t)BQ * KK * LL * RR;         //    442,368
    const size_t BCS = (size_t)BQ * KK * LL * NN;         //    589,824
    const size_t TSM = (size_t)BQ * KK * CH * DI;         //    589,824
    const size_t SBF = (size_t)BQ * KK * LL * DI;         // 14,155,776
    const size_t HST = (size_t)BQ * KK * CH * DI * NN;    //  9,437,184

    float* xcz   = wsf;                  // (B,L,768): xc half + gelu(z) half
    float* xcT   = xcz + XCZ;            // (B,L,384) fp32 conv output (scan u)
    float* xcTt  = xcT + SZ;             // (B,L,384) fp32, transposed row order
    float* dts   = xcTt + SZ;            // (B,K,L,R)
    float* Bsb   = dts + DTS;            // (B,K,L,N)
    float* Csb   = Bsb + BCS;            // (B,K,L,N)
    float* Tsum  = Csb + BCS;            // (B,K,CH,DI) chunk delta totals
    float* hstin = Tsum + TSM;           // (B,K,CH,DI,N)
    float* yk    = hstin + HST;          // (B,K,L,DI)
    short* xTbf  = (short*)(yk + SBF);   // (B,L,192) bf16 in_proj input
    short* wibf  = xTbf + (size_t)BQ * LL * DM;   // (768,192)
    short* owbf  = wibf + 768 * 192;              // (192,384)
    short* wpbf  = owbf + 192 * 384;              // (192,384) x_proj padded
    short* gbufb = wpbf + 192 * 384;              // (B,L,384) bf16 gate output
    // xcTbf (B*L*384 shorts) aliases yk: xcTbf dead after k_xproj_mfma; yk
    // first written by k_scan_pass2 (after).
    short* xcTbf = (short*)yk;

    k_prep_w<<<1152, 256, 0, stream>>>(ipw, opw, xpw, wibf, owbf, wpbf);
    k_prep_xT<<<BQ * 72 * 6, 256, 0, stream>>>(x, xTbf);
    k_inproj_mfma<<<dim3(12, 18, BQ), 256, 0, stream>>>(xTbf, wibf, xcz);
    k_dwconv<<<BQ * HH * 4, 384, 0, stream>>>(xcz, cw, cb, xcT, xcTt, xcTbf);
    k_xproj_mfma<<<dim3(3, 18, BQ), 256, 0, stream>>>(xcTbf, wpbf, dts, Bsb, Csb);

    k_scan_pass1<<<BQ * KK * CH * 2, 192, 0, stream>>>(
        xcT, xcTt, dts, Bsb, dtw, dtb, Alogs, hstin, Tsum);
    k_scan_combine<<<(BQ * KK * DI * NN) / 256, 256, 0, stream>>>(
        hstin, Tsum, Alogs);
    k_scan_pass2<<<BQ * KK * CH * 2, 192, 0, stream>>>(
        xcT, xcTt, dts, Bsb, Csb, dtw, dtb, Alogs, Ds, hstin, yk);
    k_merge_ln_gate<<<BQ * LL, 384, 0, stream>>>(yk, xcz, lnw, lnb, gbufb);

    k_outproj_mfma<<<dim3(3, 18, BQ), 256, 0, stream>>>(gbufb, owbf, out);
}